// Round 12
// baseline (177.052 us; speedup 1.0000x reference)
//
#include <hip/hip_runtime.h>
#include <math.h>

#define HEADS 2
#define C1    33
#define C2    550
#define D1    66     // HEADS*C1
#define D2    1100   // HEADS*C2
#define IN1   256
#define PROJW 288    // padded q|k|v|s width (264 -> 288 = 3*96)
#define KU    224    // padded U width (198 -> 224 = 7*32)
#define KZ    96     // padded K for z-GEMM (66 -> 96)
#define ZW    144    // Z row stride (136 used -> 144)

typedef __attribute__((ext_vector_type(8))) short bfrag;   // 8 bf16 (bits in short)
typedef __attribute__((ext_vector_type(4))) float f32x4;

__device__ inline unsigned short f2bf(float f) {
    unsigned int u = __float_as_uint(f);
    u += 0x7FFFu + ((u >> 16) & 1u);
    return (unsigned short)(u >> 16);
}
__device__ inline float bf2f(unsigned short u) {
    return __uint_as_float((unsigned int)u << 16);
}

// XCD-aware swizzle: blocks with equal bid%8 (same XCD) get contiguous work
// slots, so all col-groups of a row-tile run on one XCD and share its L2.
__device__ inline int xcd_slot(int bid, int slots) {
    return (bid >> 3) + (bid & 7) * slots;
}

// ---------------- Wt1 fragment-order [3][8][4][96][8] + bcat[288] ----------------
__global__ void k_prep1(const float* __restrict__ Wq, const float* __restrict__ bq,
                        const float* __restrict__ Wk, const float* __restrict__ bk,
                        const float* __restrict__ Wv, const float* __restrict__ bv,
                        const float* __restrict__ Ws, const float* __restrict__ bs,
                        unsigned short* __restrict__ Wt1, float* __restrict__ bcat) {
    int bid = blockIdx.x;            // (g*8+ks)*4+lk, 96 blocks
    int lk = bid & 3, t = bid >> 2;
    int ks = t & 7, g = t >> 3;
    int col = threadIdx.x;           // 0..95
    int c = g * 96 + col;
    int k0 = ks * 32 + lk * 8;
    short vals[8];
    float bia = 0.f;
    if (c < 4 * D1) {
        int m = c / D1, j = c % D1;
        const float* W; const float* B;
        switch (m) {
            case 0: W = Wq; B = bq; break;
            case 1: W = Wk; B = bk; break;
            case 2: W = Wv; B = bv; break;
            default: W = Ws; B = bs; break;
        }
        #pragma unroll
        for (int e = 0; e < 8; e++) vals[e] = (short)f2bf(W[(size_t)(k0 + e) * D1 + j]);
        bia = B[j];
    } else {
        #pragma unroll
        for (int e = 0; e < 8; e++) vals[e] = 0;
    }
    *(bfrag*)&Wt1[((size_t)bid * 96 + col) * 8] = *(bfrag*)vals;
    if (ks == 0 && lk == 0) bcat[c] = bia;
}

// ---------------- W2t fragment-order [12][7][4][96][8] ----------------
// rows 198/199 = head-masked bv2 (flag columns); row 223 = bs2 (const-1 column).
__global__ void k_prep2(const float* __restrict__ Wv2, const float* __restrict__ bv2,
                        const float* __restrict__ Ws2, const float* __restrict__ bs2,
                        unsigned short* __restrict__ W2t) {
    int bid = blockIdx.x;            // (g*7+ks)*4+lk, 336 blocks
    int lk = bid & 3, t = bid >> 2;
    int ks = t % 7, g = t / 7;
    int col = threadIdx.x;           // 0..95
    int c = g * 96 + col;
    int k0 = ks * 32 + lk * 8;
    short vals[8];
    #pragma unroll
    for (int e = 0; e < 8; e++) {
        int k = k0 + e;
        float val = 0.f;
        if (c < D2) {
            if (c < C2) {
                if (k < 66) val = Wv2[(size_t)k * D2 + c];
                else if (k >= 132 && k < 198) val = Ws2[(size_t)(k - 132) * D2 + c];
                else if (k == 198) val = bv2[c];
                else if (k == 223) val = bs2[c];
            } else {
                if (k >= 66 && k < 132) val = Wv2[(size_t)(k - 66) * D2 + c];
                else if (k >= 132 && k < 198) val = Ws2[(size_t)(k - 132) * D2 + c];
                else if (k == 199) val = bv2[c];
                else if (k == 223) val = bs2[c];
            }
        }
        vals[e] = (short)f2bf(val);
    }
    *(bfrag*)&W2t[((size_t)bid * 96 + col) * 8] = *(bfrag*)vals;
}

// ---------------- CSR construction ----------------
__global__ void k_hist(const int* __restrict__ dst, int E, int* __restrict__ cnt) {
    int e = blockIdx.x * blockDim.x + threadIdx.x;
    if (e < E) atomicAdd(&cnt[dst[e]], 1);
}

__global__ void k_scan(const int* __restrict__ cnt, int* __restrict__ roff,
                       int* __restrict__ pos, int N) {
    __shared__ int wsum[16];
    __shared__ int carry_s;
    int tid = threadIdx.x, wid = tid >> 6, lane = tid & 63;
    if (tid == 0) { carry_s = 0; roff[0] = 0; }
    __syncthreads();
    for (int base = 0; base < N; base += 1024) {
        int i = base + tid;
        int v = (i < N) ? cnt[i] : 0;
        int x = v;
        #pragma unroll
        for (int s = 1; s < 64; s <<= 1) {
            int t = __shfl_up(x, s, 64);
            if (lane >= s) x += t;
        }
        if (lane == 63) wsum[wid] = x;
        __syncthreads();
        if (tid < 16) {
            int y = wsum[tid];
            #pragma unroll
            for (int s = 1; s < 16; s <<= 1) {
                int t = __shfl_up(y, s, 16);
                if (tid >= s) y += t;
            }
            wsum[tid] = y;
        }
        __syncthreads();
        int carry = carry_s;
        int incl = carry + (wid ? wsum[wid - 1] : 0) + x;
        if (i < N) { roff[i + 1] = incl; pos[i] = incl - v; }
        __syncthreads();
        if (tid == 0) carry_s = carry + wsum[15];
        __syncthreads();
    }
}

__global__ void k_fill(const int* __restrict__ src, const int* __restrict__ dst, int E,
                       int* __restrict__ pos, int* __restrict__ elist) {
    int e = blockIdx.x * blockDim.x + threadIdx.x;
    if (e < E) {
        int slot = atomicAdd(&pos[dst[e]], 1);
        elist[slot] = src[e];
    }
}

// ---------------- precomp: G/wqbk/wkbq dots -> GBt fragment slots + cc ----------------
// jobs j<8976: (h,a,b): b<66 -> GBt row h*66+a, k=b; b=66 -> row 132+h, k=a;
// b=67 -> row 134+h, k=a. j=8976/8977 -> cc[h].
__global__ __launch_bounds__(256) void k_precomp(
        const float* __restrict__ Wq2, const float* __restrict__ bq2,
        const float* __restrict__ Wk2, const float* __restrict__ bk2,
        unsigned short* __restrict__ GBt, float* __restrict__ cc) {
    int wave = threadIdx.x >> 6, lane = threadIdx.x & 63;
    int j = blockIdx.x * 4 + wave;
    if (j >= 8978) return;
    const float *u, *v;
    int h = 0, a = 0, b = 0;
    if (j < 8976) {
        h = j / 4488;
        int r = j % 4488;
        a = r / 68; b = r % 68;
        if (b < 66)      { u = Wq2 + (size_t)a * D2 + h * C2; v = Wk2 + (size_t)b * D2 + h * C2; }
        else if (b == 66){ u = Wq2 + (size_t)a * D2 + h * C2; v = bk2 + h * C2; }
        else             { u = Wk2 + (size_t)a * D2 + h * C2; v = bq2 + h * C2; }
    } else {
        h = j - 8976;
        u = bq2 + h * C2; v = bk2 + h * C2;
    }
    float acc = 0.f;
    for (int c = lane; c < C2; c += 64) acc += u[c] * v[c];
    #pragma unroll
    for (int off = 32; off >= 1; off >>= 1) acc += __shfl_xor(acc, off, 64);
    if (lane == 0) {
        if (j < 8976) {
            int r, k;
            if (b < 66)      { r = h * 66 + a; k = b; }
            else if (b == 66){ r = 132 + h;    k = a; }
            else             { r = 134 + h;    k = a; }
            int g = r / 96, cm = r % 96;
            int ks2 = k >> 5, rem = k & 31, lk2 = rem >> 3, e = rem & 7;
            GBt[(((size_t)(g * 3 + ks2) * 4 + lk2) * 96 + cm) * 8 + e] = f2bf(acc);
        } else {
            cc[h] = acc;
        }
    }
}

// ---------------- MFMA GEMM 1 (fused x-convert): projb = bf16(x @ W^T + bcat) ----------------
__global__ __launch_bounds__(256) void k_mm1(
        const float* __restrict__ X, const unsigned short* __restrict__ B,
        const float* __restrict__ bias, unsigned short* __restrict__ projb, int N,
        int nRow, int slots) {
    int s = xcd_slot(blockIdx.x, slots);
    if (s >= nRow * 3) return;
    int rowt = s / 3, g = s - rowt * 3;
    int cbase = g * 96;
    int wave = threadIdx.x >> 6, lane = threadIdx.x & 63;
    int lr = lane & 15, lk = lane >> 4;
    int rbase = rowt * 128 + wave * 32;
    int ar[2];
    #pragma unroll
    for (int mi = 0; mi < 2; mi++) {
        int r = rbase + mi * 16 + lr;
        ar[mi] = (r < N) ? r : (N - 1);
    }
    bfrag a[2][8];
    #pragma unroll
    for (int mi = 0; mi < 2; mi++)
        #pragma unroll
        for (int ks = 0; ks < 8; ks++) {
            const float* p = X + (size_t)ar[mi] * IN1 + ks * 32 + lk * 8;
            float4 v0 = *(const float4*)p;
            float4 v1 = *(const float4*)(p + 4);
            bfrag r;
            r[0] = (short)f2bf(v0.x); r[1] = (short)f2bf(v0.y);
            r[2] = (short)f2bf(v0.z); r[3] = (short)f2bf(v0.w);
            r[4] = (short)f2bf(v1.x); r[5] = (short)f2bf(v1.y);
            r[6] = (short)f2bf(v1.z); r[7] = (short)f2bf(v1.w);
            a[mi][ks] = r;
        }
    f32x4 acc[2][6];
    #pragma unroll
    for (int mi = 0; mi < 2; mi++)
        #pragma unroll
        for (int ni = 0; ni < 6; ni++) acc[mi][ni] = (f32x4){0.f, 0.f, 0.f, 0.f};
    #pragma unroll
    for (int ks = 0; ks < 8; ks++) {
        bfrag b[6];
        #pragma unroll
        for (int ni = 0; ni < 6; ni++)
            b[ni] = *(const bfrag*)(B + (size_t)(g * 8 + ks) * 3072 + lk * 768 + (ni * 16 + lr) * 8);
        #pragma unroll
        for (int mi = 0; mi < 2; mi++)
            #pragma unroll
            for (int ni = 0; ni < 6; ni++)
                acc[mi][ni] = __builtin_amdgcn_mfma_f32_16x16x32_bf16(a[mi][ks], b[ni], acc[mi][ni], 0, 0, 0);
    }
    #pragma unroll
    for (int mi = 0; mi < 2; mi++) {
        #pragma unroll
        for (int ni = 0; ni < 6; ni++) {
            int col = cbase + ni * 16 + lr;
            float bia = bias[col];
            #pragma unroll
            for (int r = 0; r < 4; r++) {
                int row = rbase + mi * 16 + lk * 4 + r;
                if (row < N) projb[(size_t)row * PROJW + col] = f2bf(acc[mi][ni][r] + bia);
            }
        }
    }
}

// ---------------- conv1: wave=head, half-wave per edge; bf16 proj reads ----------------
__global__ __launch_bounds__(128) void k_conv1(
        const unsigned short* __restrict__ projb, const int* __restrict__ roff,
        const int* __restrict__ elist, unsigned short* __restrict__ h1b, int N) {
    int n = blockIdx.x;
    int h = threadIdx.x >> 6;
    int lane = threadIdx.x & 63;
    int half = lane >> 5, l32 = lane & 31;
    size_t pb = (size_t)n * PROJW;
    int hc = h * C1;
    float q_a = bf2f(projb[pb + hc + l32]);                      // dims 0..31
    float q_b = (l32 == 0) ? bf2f(projb[pb + hc + 32]) : 0.f;    // dim 32
    int E0 = roff[n], E1 = roff[n + 1];
    float m = -INFINITY, lsum = 0.f, aca = 0.f, acb = 0.f;
    const float isc = 0.17407765595569785f;  // 1/sqrt(33)
    int i = E0 + half;
    for (; i + 2 < E1; i += 4) {
        int s0 = elist[i], s1 = elist[i + 2];
        size_t b0 = (size_t)s0 * PROJW, b1 = (size_t)s1 * PROJW;
        float k0a = bf2f(projb[b0 + 66 + hc + l32]);
        float k0b = (l32 == 0) ? bf2f(projb[b0 + 66 + hc + 32]) : 0.f;
        float k1a = bf2f(projb[b1 + 66 + hc + l32]);
        float k1b = (l32 == 0) ? bf2f(projb[b1 + 66 + hc + 32]) : 0.f;
        float v0a = bf2f(projb[b0 + 132 + hc + l32]);
        float v0b = (l32 == 0) ? bf2f(projb[b0 + 132 + hc + 32]) : 0.f;
        float v1a = bf2f(projb[b1 + 132 + hc + l32]);
        float v1b = (l32 == 0) ? bf2f(projb[b1 + 132 + hc + 32]) : 0.f;
        float p0 = q_a * k0a + q_b * k0b;
        float p1 = q_a * k1a + q_b * k1b;
        #pragma unroll
        for (int off = 16; off >= 1; off >>= 1) {
            p0 += __shfl_xor(p0, off, 32);
            p1 += __shfl_xor(p1, off, 32);
        }
        float a0 = p0 * isc, a1 = p1 * isc;
        float mp = fmaxf(a0, a1);
        float e0 = __expf(a0 - mp), e1 = __expf(a1 - mp);
        float lp = e0 + e1;
        float apa = e0 * v0a + e1 * v1a;
        float apb = e0 * v0b + e1 * v1b;
        float mnew = fmaxf(m, mp);
        float sc = __expf(m - mnew), sp = __expf(mp - mnew);
        lsum = lsum * sc + lp * sp;
        aca = aca * sc + apa * sp;
        acb = acb * sc + apb * sp;
        m = mnew;
    }
    for (; i < E1; i += 2) {
        int s = elist[i];
        size_t sb = (size_t)s * PROJW;
        float ka = bf2f(projb[sb + 66 + hc + l32]);
        float kb = (l32 == 0) ? bf2f(projb[sb + 66 + hc + 32]) : 0.f;
        float va = bf2f(projb[sb + 132 + hc + l32]);
        float vb = (l32 == 0) ? bf2f(projb[sb + 132 + hc + 32]) : 0.f;
        float p = q_a * ka + q_b * kb;
        #pragma unroll
        for (int off = 16; off >= 1; off >>= 1) p += __shfl_xor(p, off, 32);
        float alpha = p * isc;
        float mnew = fmaxf(m, alpha);
        float sc = __expf(m - mnew);
        float pe = __expf(alpha - mnew);
        lsum = lsum * sc + pe;
        aca = aca * sc + pe * va;
        acb = acb * sc + pe * vb;
        m = mnew;
    }
    // merge the two halves (register shuffles across lane^32; -inf safe)
    float mO  = __shfl_xor(m, 32, 64);
    float lO  = __shfl_xor(lsum, 32, 64);
    float aaO = __shfl_xor(aca, 32, 64);
    float abO = __shfl_xor(acb, 32, 64);
    float mnew = fmaxf(m, mO);
    float sS = (m  > -INFINITY) ? __expf(m  - mnew) : 0.f;
    float sO = (mO > -INFINITY) ? __expf(mO - mnew) : 0.f;
    lsum = lsum * sS + lO * sO;
    aca  = aca * sS + aaO * sO;
    acb  = acb * sS + abO * sO;
    float inv = (lsum > 0.f) ? 1.f / lsum : 0.f;
    if (half == 0) {
        float s1a = bf2f(projb[pb + 198 + hc + l32]);
        float val = aca * inv + s1a;
        h1b[(size_t)n * KZ + hc + l32] = f2bf(val);
        if (l32 == 0) {
            float s1b = bf2f(projb[pb + 198 + hc + 32]);
            float valb = acb * inv + s1b;
            h1b[(size_t)n * KZ + hc + 32] = f2bf(valb);
        }
    } else if (h == 1 && l32 < 30) {
        h1b[(size_t)n * KZ + D1 + l32] = 0;   // zero pad cols 66..95
    }
}

// ---------------- MFMA GEMM z: Zb[N][144] = bf16(h1b @ GBt^T) (cols 0..135 valid) ----------------
__global__ __launch_bounds__(256) void k_mmz(
        const unsigned short* __restrict__ A, const unsigned short* __restrict__ B,
        unsigned short* __restrict__ Zb, int N, int nRow, int slots) {
    int s = xcd_slot(blockIdx.x, slots);
    if (s >= nRow * 2) return;
    int rowt = s >> 1, g = s & 1;
    int wave = threadIdx.x >> 6, lane = threadIdx.x & 63;
    int lr = lane & 15, lk = lane >> 4;
    int rbase = rowt * 64 + (wave >> 1) * 32;
    int ch = (wave & 1) * 48;
    int cbase = g * 96 + ch;
    f32x4 acc[2][3];
    #pragma unroll
    for (int i = 0; i < 2; i++)
        #pragma unroll
        for (int j = 0; j < 3; j++) acc[i][j] = (f32x4){0.f, 0.f, 0.f, 0.f};
    int ar[2];
    #pragma unroll
    for (int mi = 0; mi < 2; mi++) {
        int r = rbase + mi * 16 + lr;
        ar[mi] = (r < N) ? r : (N - 1);
    }
    #pragma unroll
    for (int ks = 0; ks < 3; ks++) {
        bfrag a[2], b[3];
        #pragma unroll
        for (int mi = 0; mi < 2; mi++)
            a[mi] = *(const bfrag*)(A + (size_t)ar[mi] * KZ + ks * 32 + lk * 8);
        #pragma unroll
        for (int ni = 0; ni < 3; ni++)
            b[ni] = *(const bfrag*)(B + (size_t)(g * 3 + ks) * 3072 + lk * 768 + (ch + ni * 16 + lr) * 8);
        #pragma unroll
        for (int mi = 0; mi < 2; mi++)
            #pragma unroll
            for (int ni = 0; ni < 3; ni++)
                acc[mi][ni] = __builtin_amdgcn_mfma_f32_16x16x32_bf16(a[mi], b[ni], acc[mi][ni], 0, 0, 0);
    }
    #pragma unroll
    for (int mi = 0; mi < 2; mi++) {
        #pragma unroll
        for (int ni = 0; ni < 3; ni++) {
            int col = cbase + ni * 16 + lr;
            if (col >= 136) continue;
            #pragma unroll
            for (int r = 0; r < 4; r++) {
                int row = rbase + mi * 16 + lk * 4 + r;
                if (row < N) Zb[(size_t)row * ZW + col] = f2bf(acc[mi][ni][r]);
            }
        }
    }
}

// ---------------- conv2: wave=head, half-wave per edge; all-bf16 gathers ----------------
__global__ __launch_bounds__(128) void k_conv2(
        const unsigned short* __restrict__ h1b, const unsigned short* __restrict__ Zb,
        const float* __restrict__ cc, const int* __restrict__ roff,
        const int* __restrict__ elist, unsigned short* __restrict__ U, int N) {
    int n = blockIdx.x;
    int h = threadIdx.x >> 6;
    int lane = threadIdx.x & 63;
    int half = lane >> 5, l32 = lane & 31;
    int hD = h * D1;
    size_t nb = (size_t)n * KZ;
    float hd_a = bf2f(h1b[nb + l32]);                         // dims 0..31
    float hd_b = bf2f(h1b[nb + 32 + l32]);                    // dims 32..63
    float hd_c = (l32 < 2) ? bf2f(h1b[nb + 64 + l32]) : 0.f;  // dims 64,65
    float adv = bf2f(Zb[(size_t)n * ZW + 132 + h]) + cc[h];
    int E0 = roff[n], E1 = roff[n + 1];
    float m = -INFINITY, lsum = 0.f, aa = 0.f, ab = 0.f, ac = 0.f;
    const float isc = 0.04264014327112209f;  // 1/sqrt(550)
    int i = E0 + half;
    for (; i + 2 < E1; i += 4) {
        int s0 = elist[i], s1 = elist[i + 2];
        const unsigned short* z0 = Zb + (size_t)s0 * ZW;
        const unsigned short* z1 = Zb + (size_t)s1 * ZW;
        float z0c = (l32 < 2) ? bf2f(z0[hD + 64 + l32]) : 0.f;
        float z1c = (l32 < 2) ? bf2f(z1[hD + 64 + l32]) : 0.f;
        float p0 = hd_a * bf2f(z0[hD + l32]) + hd_b * bf2f(z0[hD + 32 + l32]) + hd_c * z0c;
        float p1 = hd_a * bf2f(z1[hD + l32]) + hd_b * bf2f(z1[hD + 32 + l32]) + hd_c * z1c;
        float as0 = bf2f(z0[134 + h]), as1 = bf2f(z1[134 + h]);
        #pragma unroll
        for (int off = 16; off >= 1; off >>= 1) {
            p0 += __shfl_xor(p0, off, 32);
            p1 += __shfl_xor(p1, off, 32);
        }
        float al0 = (p0 + adv + as0) * isc;
        float al1 = (p1 + adv + as1) * isc;
        size_t v0b = (size_t)s0 * KZ, v1b = (size_t)s1 * KZ;
        float v0a = bf2f(h1b[v0b + l32]), v0bb = bf2f(h1b[v0b + 32 + l32]);
        float v0c = (l32 < 2) ? bf2f(h1b[v0b + 64 + l32]) : 0.f;
        float v1a = bf2f(h1b[v1b + l32]), v1bb = bf2f(h1b[v1b + 32 + l32]);
        float v1c = (l32 < 2) ? bf2f(h1b[v1b + 64 + l32]) : 0.f;
        float mp = fmaxf(al0, al1);
        float e0 = __expf(al0 - mp), e1 = __expf(al1 - mp);
        float lp = e0 + e1;
        float mnew = fmaxf(m, mp);
        float sc = __expf(m - mnew), sp = __expf(mp - mnew);
        lsum = lsum * sc + lp * sp;
        aa = aa * sc + (e0 * v0a + e1 * v1a) * sp;
        ab = ab * sc + (e0 * v0bb + e1 * v1bb) * sp;
        ac = ac * sc + (e0 * v0c + e1 * v1c) * sp;
        m = mnew;
    }
    for (; i < E1; i += 2) {
        int s = elist[i];
        const unsigned short* zr = Zb + (size_t)s * ZW;
        float zc = (l32 < 2) ? bf2f(zr[hD + 64 + l32]) : 0.f;
        float p = hd_a * bf2f(zr[hD + l32]) + hd_b * bf2f(zr[hD + 32 + l32]) + hd_c * zc;
        float as_ = bf2f(zr[134 + h]);
        #pragma unroll
        for (int off = 16; off >= 1; off >>= 1) p += __shfl_xor(p, off, 32);
        float alpha = (p + adv + as_) * isc;
        size_t vb = (size_t)s * KZ;
        float va = bf2f(h1b[vb + l32]), vbb = bf2f(h1b[vb + 32 + l32]);
        float vc = (l32 < 2) ? bf2f(h1b[vb + 64 + l32]) : 0.f;
        float mnew = fmaxf(m, alpha);
        float sc = __expf(m - mnew);
        float pe = __expf(alpha - mnew);
        lsum = lsum * sc + pe;
        aa = aa * sc + pe * va;
        ab = ab * sc + pe * vbb;
        ac = ac * sc + pe * vc;
        m = mnew;
    }
    // merge halves (register shuffles across lane^32; -inf safe)
    float mO  = __shfl_xor(m, 32, 64);
    float lO  = __shfl_xor(lsum, 32, 64);
    float aaO = __shfl_xor(aa, 32, 64);
    float abO = __shfl_xor(ab, 32, 64);
    float acO = __shfl_xor(ac, 32, 64);
    float mnew = fmaxf(m, mO);
    float sS = (m  > -INFINITY) ? __expf(m  - mnew) : 0.f;
    float sO = (mO > -INFINITY) ? __expf(mO - mnew) : 0.f;
    lsum = lsum * sS + lO * sO;
    aa = aa * sS + aaO * sO;
    ab = ab * sS + abO * sO;
    ac = ac * sS + acO * sO;
    float inv = (lsum > 0.f) ? 1.f / lsum : 0.f;
    size_t ub = (size_t)n * KU;
    if (half == 0) {
        U[ub + hD + l32] = f2bf(aa * inv);
        if (l32 < 2) U[ub + hD + 64 + l32] = f2bf(ac * inv);
    } else {
        U[ub + hD + 32 + l32] = f2bf(ab * inv);
    }
    if (lane == 0) U[ub + 198 + h] = (lsum > 0.f) ? (unsigned short)0x3F80 : (unsigned short)0;
    if (h == 0) {
        if (half == 0) {
            U[ub + 132 + l32] = f2bf(hd_a);
            if (l32 < 2) U[ub + 132 + 64 + l32] = f2bf(hd_c);
            if (l32 == 2) U[ub + 223] = (unsigned short)0x3F80;   // const-1 col (bias)
        } else {
            U[ub + 132 + 32 + l32] = f2bf(hd_b);
        }
    } else if (half == 1 && l32 < 23) {
        U[ub + 200 + l32] = 0;                                    // zero pad 200..222
    }
}

// ---------------- MFMA GEMM 2: out = pairmax(U @ W2t^T); bias/flag folded into K ----------------
__global__ __launch_bounds__(256) void k_mm2(
        const unsigned short* __restrict__ A, const unsigned short* __restrict__ B,
        float* __restrict__ out, int N, int nRow, int slots) {
    __shared__ float ot[4][32][49];
    int s = xcd_slot(blockIdx.x, slots);
    if (s >= nRow * 12) return;
    int rowt = s / 12, g = s - rowt * 12;
    int wave = threadIdx.x >> 6, lane = threadIdx.x & 63;
    int lr = lane & 15, lk = lane >> 4;
    int rbase = rowt * 128 + wave * 32;
    int ar[2];
    #pragma unroll
    for (int mi = 0; mi < 2; mi++) {
        int r = rbase + mi * 16 + lr;
        ar[mi] = (r < N) ? r : (N - 1);
    }
    bfrag a[2][7];
    #pragma unroll
    for (int mi = 0; mi < 2; mi++)
        #pragma unroll
        for (int ks = 0; ks < 7; ks++)
            a[mi][ks] = *(const bfrag*)(A + (size_t)ar[mi] * KU + ks * 32 + lk * 8);
    f32x4 acc[2][6];
    #pragma unroll
    for (int mi = 0; mi < 2; mi++)
        #pragma unroll
        for (int ni = 0; ni < 6; ni++) acc[mi][ni] = (f32x4){0.f, 0.f, 0.f, 0.f};
    #pragma unroll
    for (int ks = 0; ks < 7; ks++) {
        bfrag b[6];
        #pragma unroll
        for (int ni = 0; ni < 6; ni++)
            b[ni] = *(const bfrag*)(B + (size_t)(g * 7 + ks) * 3072 + lk * 768 + (ni * 16 + lr) * 8);
        #pragma unroll
        for (int mi = 0; mi < 2; mi++)
            #pragma unroll
            for (int ni = 0; ni < 6; ni++)
                acc[mi][ni] = __builtin_amdgcn_mfma_f32_16x16x32_bf16(a[mi][ks], b[ni], acc[mi][ni], 0, 0, 0);
    }
    // pair-max into per-wave LDS tile
    #pragma unroll
    for (int mi = 0; mi < 2; mi++) {
        #pragma unroll
        for (int ni = 0; ni < 6; ni++) {
            #pragma unroll
            for (int r = 0; r < 4; r++) {
                float val = acc[mi][ni][r];
                float oth = __shfl_xor(val, 1, 64);
                if (!(lane & 1))
                    ot[wave][mi * 16 + lk * 4 + r][ni * 8 + (lr >> 1)] = fmaxf(val, oth);
            }
        }
    }
    __syncthreads();
    // coalesced write: 32 rows x 48 cols per wave
    int colb = g * 48;
    #pragma unroll
    for (int i = 0; i < 24; i++) {
        int t = i * 64 + lane;
        int r32 = t / 48, pos = t - r32 * 48;
        int row = rbase + r32;
        int col = colb + pos;
        if (row < N && col < C2)
            out[(size_t)row * C2 + col] = ot[wave][r32][pos];
    }
}

// ---------------- launcher ----------------
extern "C" void kernel_launch(void* const* d_in, const int* in_sizes, int n_in,
                              void* d_out, int out_size, void* d_ws, size_t ws_size,
                              hipStream_t stream) {
    const float* x  = (const float*)d_in[0];
    const int*   ei = (const int*)d_in[1];
    int N = in_sizes[0] / IN1;
    int E = in_sizes[1] / 2;
    const int* src = ei;
    const int* dst = ei + E;

    const float *Wq1 = (const float*)d_in[2],  *bq1 = (const float*)d_in[3];
    const float *Wk1 = (const float*)d_in[4],  *bk1 = (const float*)d_in[5];
    const float *Wv1 = (const float*)d_in[6],  *bv1 = (const float*)d_in[7];
    const float *Ws1 = (const float*)d_in[8],  *bs1 = (const float*)d_in[9];
    const float *Wq2 = (const float*)d_in[10], *bq2 = (const float*)d_in[11];
    const float *Wk2 = (const float*)d_in[12], *bk2 = (const float*)d_in[13];
    const float *Wv2 = (const float*)d_in[14], *bv2 = (const float*)d_in[15];
    const float *Ws2 = (const float*)d_in[16], *bs2 = (const float*)d_in[17];

    char* w = (char*)d_ws;
    size_t off = 0;
    auto take = [&](size_t bytes) { size_t o = off; off = (off + bytes + 255) & ~(size_t)255; return o; };

    unsigned short* projb = (unsigned short*)(w + take((size_t)N * PROJW * 2));
    unsigned short* Zb    = (unsigned short*)(w + take((size_t)N * ZW * 2));
    unsigned short* U     = (unsigned short*)(w + take((size_t)N * KU * 2));
    unsigned short* h1b   = (unsigned short*)(w + take((size_t)N * KZ * 2));
    float* cc   = (float*)(w + take(2 * 4));
    unsigned short* GBt = (unsigned short*)(w + take((size_t)24 * 96 * 8 * 2));
    unsigned short* Wt1 = (unsigned short*)(w + take((size_t)96 * 96 * 8 * 2));
    float* bcat = (float*)(w + take(PROJW * 4));
    unsigned short* W2t = (unsigned short*)(w + take((size_t)336 * 96 * 8 * 2));
    int* cnt   = (int*)(w + take((size_t)N * 4));
    int* roff  = (int*)(w + take((size_t)(N + 1) * 4));
    int* pos   = (int*)(w + take((size_t)N * 4));
    int* elist = (int*)(w + take((size_t)E * 4));

    // CSR by dst
    hipMemsetAsync(cnt, 0, (size_t)N * sizeof(int), stream);
    k_hist<<<(E + 255) / 256, 256, 0, stream>>>(dst, E, cnt);
    k_scan<<<1, 1024, 0, stream>>>(cnt, roff, pos, N);
    k_fill<<<(E + 255) / 256, 256, 0, stream>>>(src, dst, E, pos, elist);

    // weight prep (fragment-order layouts; precomp writes GBt directly)
    k_prep1<<<96, 96, 0, stream>>>(Wq1, bq1, Wk1, bk1, Wv1, bv1, Ws1, bs1, Wt1, bcat);
    k_prep2<<<336, 96, 0, stream>>>(Wv2, bv2, Ws2, bs2, W2t);
    k_precomp<<<(8978 + 3) / 4, 256, 0, stream>>>(Wq2, bq2, Wk2, bk2, GBt, cc);

    // grid sizes with XCD swizzle padding
    int nRow1 = (N + 127) / 128;
    int tot1  = nRow1 * 3;
    int slots1 = (tot1 + 7) / 8;
    int nRowZ = (N + 63) / 64;
    int totZ  = nRowZ * 2;
    int slotsZ = (totZ + 7) / 8;
    int nRow2 = (N + 127) / 128;
    int tot2  = nRow2 * 12;
    int slots2 = (tot2 + 7) / 8;

    // conv1: projections (MFMA, fused x->bf16 convert) + edge phase
    k_mm1<<<slots1 * 8, 256, 0, stream>>>(x, Wt1, bcat, projb, N, nRow1, slots1);
    k_conv1<<<N, 128, 0, stream>>>(projb, roff, elist, h1b, N);

    // z-GEMM (MFMA, bf16 output)
    k_mmz<<<slotsZ * 8, 256, 0, stream>>>(h1b, GBt, Zb, N, nRowZ, slotsZ);

    // conv2 edge phase (bf16 gathers; writes U: agg + h1 copy + flag/one columns)
    k_conv2<<<N, 128, 0, stream>>>(h1b, Zb, cc, roff, elist, U, N);

    // final fused GEMM (bias/flag folded into K) + pair-max epilogue
    k_mm2<<<slots2 * 8, 256, 0, stream>>>(U, W2t, (float*)d_out, N, nRow2, slots2);
}

// Round 15
// 175.739 us; speedup vs baseline: 1.0075x; 1.0075x over previous
//
#include <hip/hip_runtime.h>
#include <math.h>

#define HEADS 2
#define C1    33
#define C2    550
#define D1    66     // HEADS*C1
#define D2    1100   // HEADS*C2
#define IN1   256
#define PROJW 288    // padded q|k|v|s width (264 -> 288 = 3*96)
#define KU    224    // padded U width (198 -> 224 = 7*32)
#define KZ    96     // padded K for z-GEMM (66 -> 96)
#define ZW    144    // Z row stride (136 used -> 144)
#define AUW   232    // LDS A-tile row stride in shorts (464 B = 29*16: aligned, 2-way banks)

typedef __attribute__((ext_vector_type(8))) short bfrag;   // 8 bf16 (bits in short)
typedef __attribute__((ext_vector_type(4))) float f32x4;

__device__ inline unsigned short f2bf(float f) {
    unsigned int u = __float_as_uint(f);
    u += 0x7FFFu + ((u >> 16) & 1u);
    return (unsigned short)(u >> 16);
}

// XCD-aware swizzle: blocks with equal bid%8 (same XCD) get contiguous work
// slots, so all col-groups of a row-tile run on one XCD and share its L2.
__device__ inline int xcd_slot(int bid, int slots) {
    return (bid >> 3) + (bid & 7) * slots;
}

// ---------------- Wt1 fragment-order [3][8][4][96][8] + bcat[288] ----------------
__global__ void k_prep1(const float* __restrict__ Wq, const float* __restrict__ bq,
                        const float* __restrict__ Wk, const float* __restrict__ bk,
                        const float* __restrict__ Wv, const float* __restrict__ bv,
                        const float* __restrict__ Ws, const float* __restrict__ bs,
                        unsigned short* __restrict__ Wt1, float* __restrict__ bcat) {
    int bid = blockIdx.x;            // (g*8+ks)*4+lk, 96 blocks
    int lk = bid & 3, t = bid >> 2;
    int ks = t & 7, g = t >> 3;
    int col = threadIdx.x;           // 0..95
    int c = g * 96 + col;
    int k0 = ks * 32 + lk * 8;
    short vals[8];
    float bia = 0.f;
    if (c < 4 * D1) {
        int m = c / D1, j = c % D1;
        const float* W; const float* B;
        switch (m) {
            case 0: W = Wq; B = bq; break;
            case 1: W = Wk; B = bk; break;
            case 2: W = Wv; B = bv; break;
            default: W = Ws; B = bs; break;
        }
        #pragma unroll
        for (int e = 0; e < 8; e++) vals[e] = (short)f2bf(W[(size_t)(k0 + e) * D1 + j]);
        bia = B[j];
    } else {
        #pragma unroll
        for (int e = 0; e < 8; e++) vals[e] = 0;
    }
    *(bfrag*)&Wt1[((size_t)bid * 96 + col) * 8] = *(bfrag*)vals;
    if (ks == 0 && lk == 0) bcat[c] = bia;
}

// ---------------- W2t fragment-order [12][7][4][96][8] ----------------
// rows 198/199 = head-masked bv2 (flag columns); row 223 = bs2 (const-1 column).
__global__ void k_prep2(const float* __restrict__ Wv2, const float* __restrict__ bv2,
                        const float* __restrict__ Ws2, const float* __restrict__ bs2,
                        unsigned short* __restrict__ W2t) {
    int bid = blockIdx.x;            // (g*7+ks)*4+lk, 336 blocks
    int lk = bid & 3, t = bid >> 2;
    int ks = t % 7, g = t / 7;
    int col = threadIdx.x;           // 0..95
    int c = g * 96 + col;
    int k0 = ks * 32 + lk * 8;
    short vals[8];
    #pragma unroll
    for (int e = 0; e < 8; e++) {
        int k = k0 + e;
        float val = 0.f;
        if (c < D2) {
            if (c < C2) {
                if (k < 66) val = Wv2[(size_t)k * D2 + c];
                else if (k >= 132 && k < 198) val = Ws2[(size_t)(k - 132) * D2 + c];
                else if (k == 198) val = bv2[c];
                else if (k == 223) val = bs2[c];
            } else {
                if (k >= 66 && k < 132) val = Wv2[(size_t)(k - 66) * D2 + c];
                else if (k >= 132 && k < 198) val = Ws2[(size_t)(k - 132) * D2 + c];
                else if (k == 199) val = bv2[c];
                else if (k == 223) val = bs2[c];
            }
        }
        vals[e] = (short)f2bf(val);
    }
    *(bfrag*)&W2t[((size_t)bid * 96 + col) * 8] = *(bfrag*)vals;
}

// ---------------- CSR construction ----------------
__global__ void k_hist(const int* __restrict__ dst, int E, int* __restrict__ cnt) {
    int e = blockIdx.x * blockDim.x + threadIdx.x;
    if (e < E) atomicAdd(&cnt[dst[e]], 1);
}

__global__ void k_scan(const int* __restrict__ cnt, int* __restrict__ roff,
                       int* __restrict__ pos, int N) {
    __shared__ int wsum[16];
    __shared__ int carry_s;
    int tid = threadIdx.x, wid = tid >> 6, lane = tid & 63;
    if (tid == 0) { carry_s = 0; roff[0] = 0; }
    __syncthreads();
    for (int base = 0; base < N; base += 1024) {
        int i = base + tid;
        int v = (i < N) ? cnt[i] : 0;
        int x = v;
        #pragma unroll
        for (int s = 1; s < 64; s <<= 1) {
            int t = __shfl_up(x, s, 64);
            if (lane >= s) x += t;
        }
        if (lane == 63) wsum[wid] = x;
        __syncthreads();
        if (tid < 16) {
            int y = wsum[tid];
            #pragma unroll
            for (int s = 1; s < 16; s <<= 1) {
                int t = __shfl_up(y, s, 16);
                if (tid >= s) y += t;
            }
            wsum[tid] = y;
        }
        __syncthreads();
        int carry = carry_s;
        int incl = carry + (wid ? wsum[wid - 1] : 0) + x;
        if (i < N) { roff[i + 1] = incl; pos[i] = incl - v; }
        __syncthreads();
        if (tid == 0) carry_s = carry + wsum[15];
        __syncthreads();
    }
}

__global__ void k_fill(const int* __restrict__ src, const int* __restrict__ dst, int E,
                       int* __restrict__ pos, int* __restrict__ elist) {
    int e = blockIdx.x * blockDim.x + threadIdx.x;
    if (e < E) {
        int slot = atomicAdd(&pos[dst[e]], 1);
        elist[slot] = src[e];
    }
}

// ---------------- precomp: G/wqbk/wkbq dots -> GBt fragment slots + cc ----------------
__global__ __launch_bounds__(256) void k_precomp(
        const float* __restrict__ Wq2, const float* __restrict__ bq2,
        const float* __restrict__ Wk2, const float* __restrict__ bk2,
        unsigned short* __restrict__ GBt, float* __restrict__ cc) {
    int wave = threadIdx.x >> 6, lane = threadIdx.x & 63;
    int j = blockIdx.x * 4 + wave;
    if (j >= 8978) return;
    const float *u, *v;
    int h = 0, a = 0, b = 0;
    if (j < 8976) {
        h = j / 4488;
        int r = j % 4488;
        a = r / 68; b = r % 68;
        if (b < 66)      { u = Wq2 + (size_t)a * D2 + h * C2; v = Wk2 + (size_t)b * D2 + h * C2; }
        else if (b == 66){ u = Wq2 + (size_t)a * D2 + h * C2; v = bk2 + h * C2; }
        else             { u = Wk2 + (size_t)a * D2 + h * C2; v = bq2 + h * C2; }
    } else {
        h = j - 8976;
        u = bq2 + h * C2; v = bk2 + h * C2;
    }
    float acc = 0.f;
    for (int c = lane; c < C2; c += 64) acc += u[c] * v[c];
    #pragma unroll
    for (int off = 32; off >= 1; off >>= 1) acc += __shfl_xor(acc, off, 64);
    if (lane == 0) {
        if (j < 8976) {
            int r, k;
            if (b < 66)      { r = h * 66 + a; k = b; }
            else if (b == 66){ r = 132 + h;    k = a; }
            else             { r = 134 + h;    k = a; }
            int g = r / 96, cm = r % 96;
            int ks2 = k >> 5, rem = k & 31, lk2 = rem >> 3, e = rem & 7;
            GBt[(((size_t)(g * 3 + ks2) * 4 + lk2) * 96 + cm) * 8 + e] = f2bf(acc);
        } else {
            cc[h] = acc;
        }
    }
}

// ---------------- MFMA GEMM 1 (fused x-convert): proj = x @ W^T + bcat (fp32 out) ----------------
__global__ __launch_bounds__(256) void k_mm1(
        const float* __restrict__ X, const unsigned short* __restrict__ B,
        const float* __restrict__ bias, float* __restrict__ proj, int N,
        int nRow, int slots) {
    int s = xcd_slot(blockIdx.x, slots);
    if (s >= nRow * 3) return;
    int rowt = s / 3, g = s - rowt * 3;
    int cbase = g * 96;
    int wave = threadIdx.x >> 6, lane = threadIdx.x & 63;
    int lr = lane & 15, lk = lane >> 4;
    int rbase = rowt * 128 + wave * 32;
    int ar[2];
    #pragma unroll
    for (int mi = 0; mi < 2; mi++) {
        int r = rbase + mi * 16 + lr;
        ar[mi] = (r < N) ? r : (N - 1);
    }
    bfrag a[2][8];
    #pragma unroll
    for (int mi = 0; mi < 2; mi++)
        #pragma unroll
        for (int ks = 0; ks < 8; ks++) {
            const float* p = X + (size_t)ar[mi] * IN1 + ks * 32 + lk * 8;
            float4 v0 = *(const float4*)p;
            float4 v1 = *(const float4*)(p + 4);
            bfrag r;
            r[0] = (short)f2bf(v0.x); r[1] = (short)f2bf(v0.y);
            r[2] = (short)f2bf(v0.z); r[3] = (short)f2bf(v0.w);
            r[4] = (short)f2bf(v1.x); r[5] = (short)f2bf(v1.y);
            r[6] = (short)f2bf(v1.z); r[7] = (short)f2bf(v1.w);
            a[mi][ks] = r;
        }
    f32x4 acc[2][6];
    #pragma unroll
    for (int mi = 0; mi < 2; mi++)
        #pragma unroll
        for (int ni = 0; ni < 6; ni++) acc[mi][ni] = (f32x4){0.f, 0.f, 0.f, 0.f};
    #pragma unroll
    for (int ks = 0; ks < 8; ks++) {
        bfrag b[6];
        #pragma unroll
        for (int ni = 0; ni < 6; ni++)
            b[ni] = *(const bfrag*)(B + (size_t)(g * 8 + ks) * 3072 + lk * 768 + (ni * 16 + lr) * 8);
        #pragma unroll
        for (int mi = 0; mi < 2; mi++)
            #pragma unroll
            for (int ni = 0; ni < 6; ni++)
                acc[mi][ni] = __builtin_amdgcn_mfma_f32_16x16x32_bf16(a[mi][ks], b[ni], acc[mi][ni], 0, 0, 0);
    }
    #pragma unroll
    for (int mi = 0; mi < 2; mi++) {
        #pragma unroll
        for (int ni = 0; ni < 6; ni++) {
            int col = cbase + ni * 16 + lr;
            float bia = bias[col];
            #pragma unroll
            for (int r = 0; r < 4; r++) {
                int row = rbase + mi * 16 + lk * 4 + r;
                if (row < N) proj[(size_t)row * PROJW + col] = acc[mi][ni][r] + bia;
            }
        }
    }
}

// ---------------- conv1: wave=head, half-wave per edge (dims via l32) ----------------
__global__ __launch_bounds__(128) void k_conv1(
        const float* __restrict__ proj, const int* __restrict__ roff,
        const int* __restrict__ elist, float* __restrict__ h1,
        unsigned short* __restrict__ h1b, int N) {
    int n = blockIdx.x;
    int h = threadIdx.x >> 6;
    int lane = threadIdx.x & 63;
    int half = lane >> 5, l32 = lane & 31;
    size_t pb = (size_t)n * PROJW;
    int hc = h * C1;
    float q_a = proj[pb + hc + l32];                      // dims 0..31
    float q_b = (l32 == 0) ? proj[pb + hc + 32] : 0.f;    // dim 32
    int E0 = roff[n], E1 = roff[n + 1];
    float m = -INFINITY, lsum = 0.f, aca = 0.f, acb = 0.f;
    const float isc = 0.17407765595569785f;  // 1/sqrt(33)
    int i = E0 + half;
    for (; i + 2 < E1; i += 4) {
        int s0 = elist[i], s1 = elist[i + 2];
        size_t b0 = (size_t)s0 * PROJW, b1 = (size_t)s1 * PROJW;
        float k0a = proj[b0 + 66 + hc + l32];
        float k0b = (l32 == 0) ? proj[b0 + 66 + hc + 32] : 0.f;
        float k1a = proj[b1 + 66 + hc + l32];
        float k1b = (l32 == 0) ? proj[b1 + 66 + hc + 32] : 0.f;
        float v0a = proj[b0 + 132 + hc + l32];
        float v0b = (l32 == 0) ? proj[b0 + 132 + hc + 32] : 0.f;
        float v1a = proj[b1 + 132 + hc + l32];
        float v1b = (l32 == 0) ? proj[b1 + 132 + hc + 32] : 0.f;
        float p0 = q_a * k0a + q_b * k0b;
        float p1 = q_a * k1a + q_b * k1b;
        #pragma unroll
        for (int off = 16; off >= 1; off >>= 1) {
            p0 += __shfl_xor(p0, off, 32);
            p1 += __shfl_xor(p1, off, 32);
        }
        float a0 = p0 * isc, a1 = p1 * isc;
        float mp = fmaxf(a0, a1);
        float e0 = __expf(a0 - mp), e1 = __expf(a1 - mp);
        float lp = e0 + e1;
        float apa = e0 * v0a + e1 * v1a;
        float apb = e0 * v0b + e1 * v1b;
        float mnew = fmaxf(m, mp);
        float sc = __expf(m - mnew), sp = __expf(mp - mnew);
        lsum = lsum * sc + lp * sp;
        aca = aca * sc + apa * sp;
        acb = acb * sc + apb * sp;
        m = mnew;
    }
    for (; i < E1; i += 2) {
        int s = elist[i];
        size_t sb = (size_t)s * PROJW;
        float ka = proj[sb + 66 + hc + l32];
        float kb = (l32 == 0) ? proj[sb + 66 + hc + 32] : 0.f;
        float va = proj[sb + 132 + hc + l32];
        float vb = (l32 == 0) ? proj[sb + 132 + hc + 32] : 0.f;
        float p = q_a * ka + q_b * kb;
        #pragma unroll
        for (int off = 16; off >= 1; off >>= 1) p += __shfl_xor(p, off, 32);
        float alpha = p * isc;
        float mnew = fmaxf(m, alpha);
        float sc = __expf(m - mnew);
        float pe = __expf(alpha - mnew);
        lsum = lsum * sc + pe;
        aca = aca * sc + pe * va;
        acb = acb * sc + pe * vb;
        m = mnew;
    }
    // merge the two halves (register shuffles across lane^32; -inf safe)
    float mO  = __shfl_xor(m, 32, 64);
    float lO  = __shfl_xor(lsum, 32, 64);
    float aaO = __shfl_xor(aca, 32, 64);
    float abO = __shfl_xor(acb, 32, 64);
    float mnew = fmaxf(m, mO);
    float sS = (m  > -INFINITY) ? __expf(m  - mnew) : 0.f;
    float sO = (mO > -INFINITY) ? __expf(mO - mnew) : 0.f;
    lsum = lsum * sS + lO * sO;
    aca  = aca * sS + aaO * sO;
    acb  = acb * sS + abO * sO;
    float inv = (lsum > 0.f) ? 1.f / lsum : 0.f;
    if (half == 0) {
        float s1a = proj[pb + 198 + hc + l32];
        float val = aca * inv + s1a;
        h1[(size_t)n * D1 + hc + l32] = val;
        h1b[(size_t)n * KZ + hc + l32] = f2bf(val);
        if (l32 == 0) {
            float s1b = proj[pb + 198 + hc + 32];
            float valb = acb * inv + s1b;
            h1[(size_t)n * D1 + hc + 32] = valb;
            h1b[(size_t)n * KZ + hc + 32] = f2bf(valb);
        }
    } else if (h == 1 && l32 < 30) {
        h1b[(size_t)n * KZ + D1 + l32] = 0;   // zero pad cols 66..95
    }
}

// ---------------- MFMA GEMM z: Z[N][144] = h1b[N][96] @ GBt^T (cols 0..135 valid) ----------------
__global__ __launch_bounds__(256) void k_mmz(
        const unsigned short* __restrict__ A, const unsigned short* __restrict__ B,
        float* __restrict__ Z, int N, int nRow, int slots) {
    int s = xcd_slot(blockIdx.x, slots);
    if (s >= nRow * 2) return;
    int rowt = s >> 1, g = s & 1;
    int wave = threadIdx.x >> 6, lane = threadIdx.x & 63;
    int lr = lane & 15, lk = lane >> 4;
    int rbase = rowt * 64 + (wave >> 1) * 32;
    int ch = (wave & 1) * 48;
    int cbase = g * 96 + ch;
    f32x4 acc[2][3];
    #pragma unroll
    for (int i = 0; i < 2; i++)
        #pragma unroll
        for (int j = 0; j < 3; j++) acc[i][j] = (f32x4){0.f, 0.f, 0.f, 0.f};
    int ar[2];
    #pragma unroll
    for (int mi = 0; mi < 2; mi++) {
        int r = rbase + mi * 16 + lr;
        ar[mi] = (r < N) ? r : (N - 1);
    }
    #pragma unroll
    for (int ks = 0; ks < 3; ks++) {
        bfrag a[2], b[3];
        #pragma unroll
        for (int mi = 0; mi < 2; mi++)
            a[mi] = *(const bfrag*)(A + (size_t)ar[mi] * KZ + ks * 32 + lk * 8);
        #pragma unroll
        for (int ni = 0; ni < 3; ni++)
            b[ni] = *(const bfrag*)(B + (size_t)(g * 3 + ks) * 3072 + lk * 768 + (ch + ni * 16 + lr) * 8);
        #pragma unroll
        for (int mi = 0; mi < 2; mi++)
            #pragma unroll
            for (int ni = 0; ni < 3; ni++)
                acc[mi][ni] = __builtin_amdgcn_mfma_f32_16x16x32_bf16(a[mi], b[ni], acc[mi][ni], 0, 0, 0);
    }
    #pragma unroll
    for (int mi = 0; mi < 2; mi++) {
        #pragma unroll
        for (int ni = 0; ni < 3; ni++) {
            int col = cbase + ni * 16 + lr;
            if (col >= 136) continue;
            #pragma unroll
            for (int r = 0; r < 4; r++) {
                int row = rbase + mi * 16 + lk * 4 + r;
                if (row < N) Z[(size_t)row * ZW + col] = acc[mi][ni][r];
            }
        }
    }
}

// ---------------- conv2: wave=head, half-wave per edge (dims via l32) ----------------
__global__ __launch_bounds__(128) void k_conv2(
        const float* __restrict__ h1, const float* __restrict__ Z,
        const float* __restrict__ cc, const int* __restrict__ roff,
        const int* __restrict__ elist, unsigned short* __restrict__ U, int N) {
    int n = blockIdx.x;
    int h = threadIdx.x >> 6;
    int lane = threadIdx.x & 63;
    int half = lane >> 5, l32 = lane & 31;
    int hD = h * D1;
    size_t nb = (size_t)n * D1;
    float hd_a = h1[nb + l32];                       // dims 0..31
    float hd_b = h1[nb + 32 + l32];                  // dims 32..63
    float hd_c = (l32 < 2) ? h1[nb + 64 + l32] : 0.f; // dims 64,65
    float adv = Z[(size_t)n * ZW + 132 + h] + cc[h];
    int E0 = roff[n], E1 = roff[n + 1];
    float m = -INFINITY, lsum = 0.f, aa = 0.f, ab = 0.f, ac = 0.f;
    const float isc = 0.04264014327112209f;  // 1/sqrt(550)
    int i = E0 + half;
    for (; i + 2 < E1; i += 4) {
        int s0 = elist[i], s1 = elist[i + 2];
        const float* z0 = Z + (size_t)s0 * ZW;
        const float* z1 = Z + (size_t)s1 * ZW;
        float z0c = (l32 < 2) ? z0[hD + 64 + l32] : 0.f;
        float z1c = (l32 < 2) ? z1[hD + 64 + l32] : 0.f;
        float p0 = hd_a * z0[hD + l32] + hd_b * z0[hD + 32 + l32] + hd_c * z0c;
        float p1 = hd_a * z1[hD + l32] + hd_b * z1[hD + 32 + l32] + hd_c * z1c;
        float as0 = z0[134 + h], as1 = z1[134 + h];
        #pragma unroll
        for (int off = 16; off >= 1; off >>= 1) {
            p0 += __shfl_xor(p0, off, 32);
            p1 += __shfl_xor(p1, off, 32);
        }
        float al0 = (p0 + adv + as0) * isc;
        float al1 = (p1 + adv + as1) * isc;
        size_t v0b = (size_t)s0 * D1, v1b = (size_t)s1 * D1;
        float v0a = h1[v0b + l32], v0bb = h1[v0b + 32 + l32];
        float v0c = (l32 < 2) ? h1[v0b + 64 + l32] : 0.f;
        float v1a = h1[v1b + l32], v1bb = h1[v1b + 32 + l32];
        float v1c = (l32 < 2) ? h1[v1b + 64 + l32] : 0.f;
        float mp = fmaxf(al0, al1);
        float e0 = __expf(al0 - mp), e1 = __expf(al1 - mp);
        float lp = e0 + e1;
        float mnew = fmaxf(m, mp);
        float sc = __expf(m - mnew), sp = __expf(mp - mnew);
        lsum = lsum * sc + lp * sp;
        aa = aa * sc + (e0 * v0a + e1 * v1a) * sp;
        ab = ab * sc + (e0 * v0bb + e1 * v1bb) * sp;
        ac = ac * sc + (e0 * v0c + e1 * v1c) * sp;
        m = mnew;
    }
    for (; i < E1; i += 2) {
        int s = elist[i];
        const float* zr = Z + (size_t)s * ZW;
        float zc = (l32 < 2) ? zr[hD + 64 + l32] : 0.f;
        float p = hd_a * zr[hD + l32] + hd_b * zr[hD + 32 + l32] + hd_c * zc;
        float as_ = zr[134 + h];
        #pragma unroll
        for (int off = 16; off >= 1; off >>= 1) p += __shfl_xor(p, off, 32);
        float alpha = (p + adv + as_) * isc;
        size_t vb = (size_t)s * D1;
        float va = h1[vb + l32], vbb = h1[vb + 32 + l32];
        float vc = (l32 < 2) ? h1[vb + 64 + l32] : 0.f;
        float mnew = fmaxf(m, alpha);
        float sc = __expf(m - mnew);
        float pe = __expf(alpha - mnew);
        lsum = lsum * sc + pe;
        aa = aa * sc + pe * va;
        ab = ab * sc + pe * vbb;
        ac = ac * sc + pe * vc;
        m = mnew;
    }
    // merge halves (register shuffles across lane^32; -inf safe)
    float mO  = __shfl_xor(m, 32, 64);
    float lO  = __shfl_xor(lsum, 32, 64);
    float aaO = __shfl_xor(aa, 32, 64);
    float abO = __shfl_xor(ab, 32, 64);
    float acO = __shfl_xor(ac, 32, 64);
    float mnew = fmaxf(m, mO);
    float sS = (m  > -INFINITY) ? __expf(m  - mnew) : 0.f;
    float sO = (mO > -INFINITY) ? __expf(mO - mnew) : 0.f;
    lsum = lsum * sS + lO * sO;
    aa = aa * sS + aaO * sO;
    ab = ab * sS + abO * sO;
    ac = ac * sS + acO * sO;
    float inv = (lsum > 0.f) ? 1.f / lsum : 0.f;
    size_t ub = (size_t)n * KU;
    if (half == 0) {
        U[ub + hD + l32] = f2bf(aa * inv);
        if (l32 < 2) U[ub + hD + 64 + l32] = f2bf(ac * inv);
    } else {
        U[ub + hD + 32 + l32] = f2bf(ab * inv);
    }
    if (lane == 0) U[ub + 198 + h] = (lsum > 0.f) ? (unsigned short)0x3F80 : (unsigned short)0;
    if (h == 0) {
        if (half == 0) {
            U[ub + 132 + l32] = f2bf(hd_a);
            if (l32 < 2) U[ub + 132 + 64 + l32] = f2bf(hd_c);
            if (l32 == 2) U[ub + 223] = (unsigned short)0x3F80;   // const-1 col (bias)
        } else {
            U[ub + 132 + 32 + l32] = f2bf(hd_b);
        }
    } else if (half == 1 && l32 < 23) {
        U[ub + 200 + l32] = 0;                                    // zero pad 200..222
    }
}

// ---------------- MFMA GEMM 2: A staged in LDS (coalesced); bias/flag folded into K ----------------
__global__ __launch_bounds__(256) void k_mm2(
        const unsigned short* __restrict__ A, const unsigned short* __restrict__ B,
        float* __restrict__ out, int N, int nRow, int slots) {
    __shared__ __align__(16) char smem[128 * AUW * 2];         // 59392 B
    unsigned short (*au)[AUW] = (unsigned short (*)[AUW])smem; // A tile (staged)
    float (*ot)[32][49] = (float (*)[32][49])smem;             // aliased epilogue tile
    int s = xcd_slot(blockIdx.x, slots);
    if (s >= nRow * 12) return;
    int rowt = s / 12, g = s - rowt * 12;
    int tid = threadIdx.x;
    int rbb = rowt * 128;
    // coalesced stage: 128 rows x 224 cols bf16 = 128*28 chunks of 8 shorts
    #pragma unroll
    for (int it = 0; it < 14; it++) {
        int i = it * 256 + tid;
        int row = i / 28, ch = i - row * 28;
        int gr = rbb + row; if (gr >= N) gr = N - 1;
        *(bfrag*)&au[row][ch * 8] = *(const bfrag*)(A + (size_t)gr * KU + ch * 8);
    }
    int wave = tid >> 6, lane = tid & 63;
    int lr = lane & 15, lk = lane >> 4;
    int rbase = rbb + wave * 32;
    __syncthreads();
    bfrag a[2][7];
    #pragma unroll
    for (int mi = 0; mi < 2; mi++)
        #pragma unroll
        for (int ks = 0; ks < 7; ks++)
            a[mi][ks] = *(const bfrag*)&au[wave * 32 + mi * 16 + lr][ks * 32 + lk * 8];
    f32x4 acc[2][6];
    #pragma unroll
    for (int mi = 0; mi < 2; mi++)
        #pragma unroll
        for (int ni = 0; ni < 6; ni++) acc[mi][ni] = (f32x4){0.f, 0.f, 0.f, 0.f};
    #pragma unroll
    for (int ks = 0; ks < 7; ks++) {
        bfrag b[6];
        #pragma unroll
        for (int ni = 0; ni < 6; ni++)
            b[ni] = *(const bfrag*)(B + (size_t)(g * 7 + ks) * 3072 + lk * 768 + (ni * 16 + lr) * 8);
        #pragma unroll
        for (int mi = 0; mi < 2; mi++)
            #pragma unroll
            for (int ni = 0; ni < 6; ni++)
                acc[mi][ni] = __builtin_amdgcn_mfma_f32_16x16x32_bf16(a[mi][ks], b[ni], acc[mi][ni], 0, 0, 0);
    }
    __syncthreads();   // all waves done reading au before ot overwrites it
    // pair-max into per-wave LDS tile
    #pragma unroll
    for (int mi = 0; mi < 2; mi++) {
        #pragma unroll
        for (int ni = 0; ni < 6; ni++) {
            #pragma unroll
            for (int r = 0; r < 4; r++) {
                float val = acc[mi][ni][r];
                float oth = __shfl_xor(val, 1, 64);
                if (!(lane & 1))
                    ot[wave][mi * 16 + lk * 4 + r][ni * 8 + (lr >> 1)] = fmaxf(val, oth);
            }
        }
    }
    __syncthreads();
    // coalesced write: 32 rows x 48 cols per wave
    int colb = g * 48;
    #pragma unroll
    for (int i = 0; i < 24; i++) {
        int t = i * 64 + lane;
        int r32 = t / 48, pos = t - r32 * 48;
        int row = rbase + r32;
        int col = colb + pos;
        if (row < N && col < C2)
            out[(size_t)row * C2 + col] = ot[wave][r32][pos];
    }
}

// ---------------- launcher ----------------
extern "C" void kernel_launch(void* const* d_in, const int* in_sizes, int n_in,
                              void* d_out, int out_size, void* d_ws, size_t ws_size,
                              hipStream_t stream) {
    const float* x  = (const float*)d_in[0];
    const int*   ei = (const int*)d_in[1];
    int N = in_sizes[0] / IN1;
    int E = in_sizes[1] / 2;
    const int* src = ei;
    const int* dst = ei + E;

    const float *Wq1 = (const float*)d_in[2],  *bq1 = (const float*)d_in[3];
    const float *Wk1 = (const float*)d_in[4],  *bk1 = (const float*)d_in[5];
    const float *Wv1 = (const float*)d_in[6],  *bv1 = (const float*)d_in[7];
    const float *Ws1 = (const float*)d_in[8],  *bs1 = (const float*)d_in[9];
    const float *Wq2 = (const float*)d_in[10], *bq2 = (const float*)d_in[11];
    const float *Wk2 = (const float*)d_in[12], *bk2 = (const float*)d_in[13];
    const float *Wv2 = (const float*)d_in[14], *bv2 = (const float*)d_in[15];
    const float *Ws2 = (const float*)d_in[16], *bs2 = (const float*)d_in[17];

    char* w = (char*)d_ws;
    size_t off = 0;
    auto take = [&](size_t bytes) { size_t o = off; off = (off + bytes + 255) & ~(size_t)255; return o; };

    size_t proj_off = take((size_t)N * PROJW * 4);
    float* proj = (float*)(w + proj_off);
    // aliased into proj region AFTER conv1 consumes proj:
    float* Z = proj;                                                       // N*144*4 = 11.52 MB
    unsigned short* U = (unsigned short*)(w + proj_off + (size_t)N * ZW * 4);  // N*224*2 = 8.96 MB
    float* h1   = (float*)(w + take((size_t)N * D1 * 4));
    unsigned short* h1b = (unsigned short*)(w + take((size_t)N * KZ * 2));
    float* cc   = (float*)(w + take(2 * 4));
    unsigned short* GBt = (unsigned short*)(w + take((size_t)24 * 96 * 8 * 2));
    unsigned short* Wt1 = (unsigned short*)(w + take((size_t)96 * 96 * 8 * 2));
    float* bcat = (float*)(w + take(PROJW * 4));
    unsigned short* W2t = (unsigned short*)(w + take((size_t)336 * 96 * 8 * 2));
    int* cnt   = (int*)(w + take((size_t)N * 4));
    int* roff  = (int*)(w + take((size_t)(N + 1) * 4));
    int* pos   = (int*)(w + take((size_t)N * 4));
    int* elist = (int*)(w + take((size_t)E * 4));

    // CSR by dst
    hipMemsetAsync(cnt, 0, (size_t)N * sizeof(int), stream);
    k_hist<<<(E + 255) / 256, 256, 0, stream>>>(dst, E, cnt);
    k_scan<<<1, 1024, 0, stream>>>(cnt, roff, pos, N);
    k_fill<<<(E + 255) / 256, 256, 0, stream>>>(src, dst, E, pos, elist);

    // weight prep (fragment-order layouts; precomp writes GBt directly)
    k_prep1<<<96, 96, 0, stream>>>(Wq1, bq1, Wk1, bk1, Wv1, bv1, Ws1, bs1, Wt1, bcat);
    k_prep2<<<336, 96, 0, stream>>>(Wv2, bv2, Ws2, bs2, W2t);
    k_precomp<<<(8978 + 3) / 4, 256, 0, stream>>>(Wq2, bq2, Wk2, bk2, GBt, cc);

    // grid sizes with XCD swizzle padding
    int nRow1 = (N + 127) / 128;
    int tot1  = nRow1 * 3;
    int slots1 = (tot1 + 7) / 8;
    int nRowZ = (N + 63) / 64;
    int totZ  = nRowZ * 2;
    int slotsZ = (totZ + 7) / 8;
    int nRow2 = (N + 127) / 128;
    int tot2  = nRow2 * 12;
    int slots2 = (tot2 + 7) / 8;

    // conv1: projections (MFMA, fused x->bf16 convert) + edge phase
    k_mm1<<<slots1 * 8, 256, 0, stream>>>(x, Wt1, bcat, proj, N, nRow1, slots1);
    k_conv1<<<N, 128, 0, stream>>>(proj, roff, elist, h1, h1b, N);

    // z-GEMM (MFMA)
    k_mmz<<<slotsZ * 8, 256, 0, stream>>>(h1b, GBt, Z, N, nRowZ, slotsZ);

    // conv2 edge phase (writes U: agg + h1 copy + flag/one columns)
    k_conv2<<<N, 128, 0, stream>>>(h1, Z, cc, roff, elist, U, N);

    // final fused GEMM (LDS-staged A, bias/flag folded into K) + pair-max epilogue
    k_mm2<<<slots2 * 8, 256, 0, stream>>>(U, W2t, (float*)d_out, N, nRow2, slots2);
}

// Round 16
// 162.855 us; speedup vs baseline: 1.0872x; 1.0791x over previous
//
#include <hip/hip_runtime.h>
#include <math.h>

#define HEADS 2
#define C1    33
#define C2    550
#define D1    66     // HEADS*C1
#define D2    1100   // HEADS*C2
#define IN1   256
#define PROJW 288    // padded q|k|v|s width (264 -> 288 = 3*96)
#define KU    224    // padded U width (198 -> 224 = 7*32)
#define KZ    96     // padded K for z-GEMM (66 -> 96)
#define ZW    144    // Z row stride (136 used -> 144)

typedef __attribute__((ext_vector_type(8))) short bfrag;   // 8 bf16 (bits in short)
typedef __attribute__((ext_vector_type(4))) float f32x4;

__device__ inline unsigned short f2bf(float f) {
    unsigned int u = __float_as_uint(f);
    u += 0x7FFFu + ((u >> 16) & 1u);
    return (unsigned short)(u >> 16);
}

// XCD-aware swizzle: blocks with equal bid%8 (same XCD) get contiguous work
// slots, so all col-groups of a row-tile run on one XCD and share its L2.
__device__ inline int xcd_slot(int bid, int slots) {
    return (bid >> 3) + (bid & 7) * slots;
}

// ================= mega prep: hist | Wt1 | W2t | GBt/cc (independent jobs) ==============
__global__ __launch_bounds__(256) void k_mega(
        const int* __restrict__ dst, int E, int* __restrict__ cnt, int histBlocks,
        const float* __restrict__ Wq1, const float* __restrict__ bq1,
        const float* __restrict__ Wk1, const float* __restrict__ bk1,
        const float* __restrict__ Wv1, const float* __restrict__ bv1,
        const float* __restrict__ Ws1, const float* __restrict__ bs1,
        unsigned short* __restrict__ Wt1, float* __restrict__ bcat,
        const float* __restrict__ Wv2, const float* __restrict__ bv2,
        const float* __restrict__ Ws2, const float* __restrict__ bs2,
        unsigned short* __restrict__ W2t,
        const float* __restrict__ Wq2, const float* __restrict__ bq2,
        const float* __restrict__ Wk2, const float* __restrict__ bk2,
        unsigned short* __restrict__ GBt, float* __restrict__ cc) {
    int bid = blockIdx.x;
    int tid = threadIdx.x;
    if (bid < histBlocks) {
        // -------- hist --------
        int e = bid * 256 + tid;
        if (e < E) atomicAdd(&cnt[dst[e]], 1);
        return;
    }
    bid -= histBlocks;
    if (bid < 96) {
        // -------- Wt1 fragment-order [3][8][4][96][8] + bcat --------
        if (tid >= 96) return;
        int lk = bid & 3, t = bid >> 2;
        int ks = t & 7, g = t >> 3;
        int col = tid;
        int c = g * 96 + col;
        int k0 = ks * 32 + lk * 8;
        short vals[8];
        float bia = 0.f;
        if (c < 4 * D1) {
            int m = c / D1, j = c % D1;
            const float* W; const float* B;
            switch (m) {
                case 0: W = Wq1; B = bq1; break;
                case 1: W = Wk1; B = bk1; break;
                case 2: W = Wv1; B = bv1; break;
                default: W = Ws1; B = bs1; break;
            }
            #pragma unroll
            for (int e = 0; e < 8; e++) vals[e] = (short)f2bf(W[(size_t)(k0 + e) * D1 + j]);
            bia = B[j];
        } else {
            #pragma unroll
            for (int e = 0; e < 8; e++) vals[e] = 0;
        }
        *(bfrag*)&Wt1[((size_t)bid * 96 + col) * 8] = *(bfrag*)vals;
        if (ks == 0 && lk == 0) bcat[c] = bia;
        return;
    }
    bid -= 96;
    if (bid < 336) {
        // -------- W2t fragment-order [12][7][4][96][8]; bias rows folded --------
        if (tid >= 96) return;
        int lk = bid & 3, t = bid >> 2;
        int ks = t % 7, g = t / 7;
        int col = tid;
        int c = g * 96 + col;
        int k0 = ks * 32 + lk * 8;
        short vals[8];
        #pragma unroll
        for (int e = 0; e < 8; e++) {
            int k = k0 + e;
            float val = 0.f;
            if (c < D2) {
                if (c < C2) {
                    if (k < 66) val = Wv2[(size_t)k * D2 + c];
                    else if (k >= 132 && k < 198) val = Ws2[(size_t)(k - 132) * D2 + c];
                    else if (k == 198) val = bv2[c];
                    else if (k == 223) val = bs2[c];
                } else {
                    if (k >= 66 && k < 132) val = Wv2[(size_t)(k - 66) * D2 + c];
                    else if (k >= 132 && k < 198) val = Ws2[(size_t)(k - 132) * D2 + c];
                    else if (k == 199) val = bv2[c];
                    else if (k == 223) val = bs2[c];
                }
            }
            vals[e] = (short)f2bf(val);
        }
        *(bfrag*)&W2t[((size_t)bid * 96 + col) * 8] = *(bfrag*)vals;
        return;
    }
    bid -= 336;
    {
        // -------- precomp dots -> GBt fragment slots + cc --------
        int wave = tid >> 6, lane = tid & 63;
        int j = bid * 4 + wave;
        if (j >= 8978) return;
        const float *u, *v;
        int h = 0, a = 0, b = 0;
        if (j < 8976) {
            h = j / 4488;
            int r = j % 4488;
            a = r / 68; b = r % 68;
            if (b < 66)      { u = Wq2 + (size_t)a * D2 + h * C2; v = Wk2 + (size_t)b * D2 + h * C2; }
            else if (b == 66){ u = Wq2 + (size_t)a * D2 + h * C2; v = bk2 + h * C2; }
            else             { u = Wk2 + (size_t)a * D2 + h * C2; v = bq2 + h * C2; }
        } else {
            h = j - 8976;
            u = bq2 + h * C2; v = bk2 + h * C2;
        }
        float acc = 0.f;
        for (int c = lane; c < C2; c += 64) acc += u[c] * v[c];
        #pragma unroll
        for (int off = 32; off >= 1; off >>= 1) acc += __shfl_xor(acc, off, 64);
        if (lane == 0) {
            if (j < 8976) {
                int r, k;
                if (b < 66)      { r = h * 66 + a; k = b; }
                else if (b == 66){ r = 132 + h;    k = a; }
                else             { r = 134 + h;    k = a; }
                int g = r / 96, cm = r % 96;
                int ks2 = k >> 5, rem = k & 31, lk2 = rem >> 3, e = rem & 7;
                GBt[(((size_t)(g * 3 + ks2) * 4 + lk2) * 96 + cm) * 8 + e] = f2bf(acc);
            } else {
                cc[h] = acc;
            }
        }
    }
}

// ---------------- scan ----------------
__global__ void k_scan(const int* __restrict__ cnt, int* __restrict__ roff,
                       int* __restrict__ pos, int N) {
    __shared__ int wsum[16];
    __shared__ int carry_s;
    int tid = threadIdx.x, wid = tid >> 6, lane = tid & 63;
    if (tid == 0) { carry_s = 0; roff[0] = 0; }
    __syncthreads();
    for (int base = 0; base < N; base += 1024) {
        int i = base + tid;
        int v = (i < N) ? cnt[i] : 0;
        int x = v;
        #pragma unroll
        for (int s = 1; s < 64; s <<= 1) {
            int t = __shfl_up(x, s, 64);
            if (lane >= s) x += t;
        }
        if (lane == 63) wsum[wid] = x;
        __syncthreads();
        if (tid < 16) {
            int y = wsum[tid];
            #pragma unroll
            for (int s = 1; s < 16; s <<= 1) {
                int t = __shfl_up(y, s, 16);
                if (tid >= s) y += t;
            }
            wsum[tid] = y;
        }
        __syncthreads();
        int carry = carry_s;
        int incl = carry + (wid ? wsum[wid - 1] : 0) + x;
        if (i < N) { roff[i + 1] = incl; pos[i] = incl - v; }
        __syncthreads();
        if (tid == 0) carry_s = carry + wsum[15];
        __syncthreads();
    }
}

// ================= fused: CSR fill | MFMA GEMM 1 (independent jobs) ==============
__global__ __launch_bounds__(256) void k_fillmm1(
        const int* __restrict__ src, const int* __restrict__ dst, int E,
        int* __restrict__ pos, int* __restrict__ elist, int fillBlocks,
        const float* __restrict__ X, const unsigned short* __restrict__ B,
        const float* __restrict__ bias, float* __restrict__ proj, int N,
        int nRow, int slots) {
    int bid = blockIdx.x;
    int tid = threadIdx.x;
    if (bid < fillBlocks) {
        int e = bid * 256 + tid;
        if (e < E) {
            int slot = atomicAdd(&pos[dst[e]], 1);
            elist[slot] = src[e];
        }
        return;
    }
    bid -= fillBlocks;
    // -------- mm1: proj = x @ W^T + bcat (fused fp32->bf16 A convert) --------
    int s = xcd_slot(bid, slots);
    if (s >= nRow * 3) return;
    int rowt = s / 3, g = s - rowt * 3;
    int cbase = g * 96;
    int wave = tid >> 6, lane = tid & 63;
    int lr = lane & 15, lk = lane >> 4;
    int rbase = rowt * 128 + wave * 32;
    int ar[2];
    #pragma unroll
    for (int mi = 0; mi < 2; mi++) {
        int r = rbase + mi * 16 + lr;
        ar[mi] = (r < N) ? r : (N - 1);
    }
    bfrag a[2][8];
    #pragma unroll
    for (int mi = 0; mi < 2; mi++)
        #pragma unroll
        for (int ks = 0; ks < 8; ks++) {
            const float* p = X + (size_t)ar[mi] * IN1 + ks * 32 + lk * 8;
            float4 v0 = *(const float4*)p;
            float4 v1 = *(const float4*)(p + 4);
            bfrag r;
            r[0] = (short)f2bf(v0.x); r[1] = (short)f2bf(v0.y);
            r[2] = (short)f2bf(v0.z); r[3] = (short)f2bf(v0.w);
            r[4] = (short)f2bf(v1.x); r[5] = (short)f2bf(v1.y);
            r[6] = (short)f2bf(v1.z); r[7] = (short)f2bf(v1.w);
            a[mi][ks] = r;
        }
    f32x4 acc[2][6];
    #pragma unroll
    for (int mi = 0; mi < 2; mi++)
        #pragma unroll
        for (int ni = 0; ni < 6; ni++) acc[mi][ni] = (f32x4){0.f, 0.f, 0.f, 0.f};
    #pragma unroll
    for (int ks = 0; ks < 8; ks++) {
        bfrag b[6];
        #pragma unroll
        for (int ni = 0; ni < 6; ni++)
            b[ni] = *(const bfrag*)(B + (size_t)(g * 8 + ks) * 3072 + lk * 768 + (ni * 16 + lr) * 8);
        #pragma unroll
        for (int mi = 0; mi < 2; mi++)
            #pragma unroll
            for (int ni = 0; ni < 6; ni++)
                acc[mi][ni] = __builtin_amdgcn_mfma_f32_16x16x32_bf16(a[mi][ks], b[ni], acc[mi][ni], 0, 0, 0);
    }
    #pragma unroll
    for (int mi = 0; mi < 2; mi++) {
        #pragma unroll
        for (int ni = 0; ni < 6; ni++) {
            int col = cbase + ni * 16 + lr;
            float bia = bias[col];
            #pragma unroll
            for (int r = 0; r < 4; r++) {
                int row = rbase + mi * 16 + lk * 4 + r;
                if (row < N) proj[(size_t)row * PROJW + col] = acc[mi][ni][r] + bia;
            }
        }
    }
}

// ---------------- conv1: wave=head, half-wave per edge (dims via l32) ----------------
__global__ __launch_bounds__(128) void k_conv1(
        const float* __restrict__ proj, const int* __restrict__ roff,
        const int* __restrict__ elist, float* __restrict__ h1,
        unsigned short* __restrict__ h1b, int N) {
    int n = blockIdx.x;
    int h = threadIdx.x >> 6;
    int lane = threadIdx.x & 63;
    int half = lane >> 5, l32 = lane & 31;
    size_t pb = (size_t)n * PROJW;
    int hc = h * C1;
    float q_a = proj[pb + hc + l32];                      // dims 0..31
    float q_b = (l32 == 0) ? proj[pb + hc + 32] : 0.f;    // dim 32
    int E0 = roff[n], E1 = roff[n + 1];
    float m = -INFINITY, lsum = 0.f, aca = 0.f, acb = 0.f;
    const float isc = 0.17407765595569785f;  // 1/sqrt(33)
    int i = E0 + half;
    for (; i + 2 < E1; i += 4) {
        int s0 = elist[i], s1 = elist[i + 2];
        size_t b0 = (size_t)s0 * PROJW, b1 = (size_t)s1 * PROJW;
        float k0a = proj[b0 + 66 + hc + l32];
        float k0b = (l32 == 0) ? proj[b0 + 66 + hc + 32] : 0.f;
        float k1a = proj[b1 + 66 + hc + l32];
        float k1b = (l32 == 0) ? proj[b1 + 66 + hc + 32] : 0.f;
        float v0a = proj[b0 + 132 + hc + l32];
        float v0b = (l32 == 0) ? proj[b0 + 132 + hc + 32] : 0.f;
        float v1a = proj[b1 + 132 + hc + l32];
        float v1b = (l32 == 0) ? proj[b1 + 132 + hc + 32] : 0.f;
        float p0 = q_a * k0a + q_b * k0b;
        float p1 = q_a * k1a + q_b * k1b;
        #pragma unroll
        for (int off = 16; off >= 1; off >>= 1) {
            p0 += __shfl_xor(p0, off, 32);
            p1 += __shfl_xor(p1, off, 32);
        }
        float a0 = p0 * isc, a1 = p1 * isc;
        float mp = fmaxf(a0, a1);
        float e0 = __expf(a0 - mp), e1 = __expf(a1 - mp);
        float lp = e0 + e1;
        float apa = e0 * v0a + e1 * v1a;
        float apb = e0 * v0b + e1 * v1b;
        float mnew = fmaxf(m, mp);
        float sc = __expf(m - mnew), sp = __expf(mp - mnew);
        lsum = lsum * sc + lp * sp;
        aca = aca * sc + apa * sp;
        acb = acb * sc + apb * sp;
        m = mnew;
    }
    for (; i < E1; i += 2) {
        int s = elist[i];
        size_t sb = (size_t)s * PROJW;
        float ka = proj[sb + 66 + hc + l32];
        float kb = (l32 == 0) ? proj[sb + 66 + hc + 32] : 0.f;
        float va = proj[sb + 132 + hc + l32];
        float vb = (l32 == 0) ? proj[sb + 132 + hc + 32] : 0.f;
        float p = q_a * ka + q_b * kb;
        #pragma unroll
        for (int off = 16; off >= 1; off >>= 1) p += __shfl_xor(p, off, 32);
        float alpha = p * isc;
        float mnew = fmaxf(m, alpha);
        float sc = __expf(m - mnew);
        float pe = __expf(alpha - mnew);
        lsum = lsum * sc + pe;
        aca = aca * sc + pe * va;
        acb = acb * sc + pe * vb;
        m = mnew;
    }
    // merge the two halves (register shuffles across lane^32; -inf safe)
    float mO  = __shfl_xor(m, 32, 64);
    float lO  = __shfl_xor(lsum, 32, 64);
    float aaO = __shfl_xor(aca, 32, 64);
    float abO = __shfl_xor(acb, 32, 64);
    float mnew = fmaxf(m, mO);
    float sS = (m  > -INFINITY) ? __expf(m  - mnew) : 0.f;
    float sO = (mO > -INFINITY) ? __expf(mO - mnew) : 0.f;
    lsum = lsum * sS + lO * sO;
    aca  = aca * sS + aaO * sO;
    acb  = acb * sS + abO * sO;
    float inv = (lsum > 0.f) ? 1.f / lsum : 0.f;
    if (half == 0) {
        float s1a = proj[pb + 198 + hc + l32];
        float val = aca * inv + s1a;
        h1[(size_t)n * D1 + hc + l32] = val;
        h1b[(size_t)n * KZ + hc + l32] = f2bf(val);
        if (l32 == 0) {
            float s1b = proj[pb + 198 + hc + 32];
            float valb = acb * inv + s1b;
            h1[(size_t)n * D1 + hc + 32] = valb;
            h1b[(size_t)n * KZ + hc + 32] = f2bf(valb);
        }
    } else if (h == 1 && l32 < 30) {
        h1b[(size_t)n * KZ + D1 + l32] = 0;   // zero pad cols 66..95
    }
}

// ---------------- MFMA GEMM z: Z[N][144] = h1b[N][96] @ GBt^T (cols 0..135 valid) ----------------
__global__ __launch_bounds__(256) void k_mmz(
        const unsigned short* __restrict__ A, const unsigned short* __restrict__ B,
        float* __restrict__ Z, int N, int nRow, int slots) {
    int s = xcd_slot(blockIdx.x, slots);
    if (s >= nRow * 2) return;
    int rowt = s >> 1, g = s & 1;
    int wave = threadIdx.x >> 6, lane = threadIdx.x & 63;
    int lr = lane & 15, lk = lane >> 4;
    int rbase = rowt * 64 + (wave >> 1) * 32;
    int ch = (wave & 1) * 48;
    int cbase = g * 96 + ch;
    f32x4 acc[2][3];
    #pragma unroll
    for (int i = 0; i < 2; i++)
        #pragma unroll
        for (int j = 0; j < 3; j++) acc[i][j] = (f32x4){0.f, 0.f, 0.f, 0.f};
    int ar[2];
    #pragma unroll
    for (int mi = 0; mi < 2; mi++) {
        int r = rbase + mi * 16 + lr;
        ar[mi] = (r < N) ? r : (N - 1);
    }
    #pragma unroll
    for (int ks = 0; ks < 3; ks++) {
        bfrag a[2], b[3];
        #pragma unroll
        for (int mi = 0; mi < 2; mi++)
            a[mi] = *(const bfrag*)(A + (size_t)ar[mi] * KZ + ks * 32 + lk * 8);
        #pragma unroll
        for (int ni = 0; ni < 3; ni++)
            b[ni] = *(const bfrag*)(B + (size_t)(g * 3 + ks) * 3072 + lk * 768 + (ch + ni * 16 + lr) * 8);
        #pragma unroll
        for (int mi = 0; mi < 2; mi++)
            #pragma unroll
            for (int ni = 0; ni < 3; ni++)
                acc[mi][ni] = __builtin_amdgcn_mfma_f32_16x16x32_bf16(a[mi], b[ni], acc[mi][ni], 0, 0, 0);
    }
    #pragma unroll
    for (int mi = 0; mi < 2; mi++) {
        #pragma unroll
        for (int ni = 0; ni < 3; ni++) {
            int col = cbase + ni * 16 + lr;
            if (col >= 136) continue;
            #pragma unroll
            for (int r = 0; r < 4; r++) {
                int row = rbase + mi * 16 + lk * 4 + r;
                if (row < N) Z[(size_t)row * ZW + col] = acc[mi][ni][r];
            }
        }
    }
}

// ---------------- conv2: wave=head, half-wave per edge (dims via l32) ----------------
__global__ __launch_bounds__(128) void k_conv2(
        const float* __restrict__ h1, const float* __restrict__ Z,
        const float* __restrict__ cc, const int* __restrict__ roff,
        const int* __restrict__ elist, unsigned short* __restrict__ U, int N) {
    int n = blockIdx.x;
    int h = threadIdx.x >> 6;
    int lane = threadIdx.x & 63;
    int half = lane >> 5, l32 = lane & 31;
    int hD = h * D1;
    size_t nb = (size_t)n * D1;
    float hd_a = h1[nb + l32];                       // dims 0..31
    float hd_b = h1[nb + 32 + l32];                  // dims 32..63
    float hd_c = (l32 < 2) ? h1[nb + 64 + l32] : 0.f; // dims 64,65
    float adv = Z[(size_t)n * ZW + 132 + h] + cc[h];
    int E0 = roff[n], E1 = roff[n + 1];
    float m = -INFINITY, lsum = 0.f, aa = 0.f, ab = 0.f, ac = 0.f;
    const float isc = 0.04264014327112209f;  // 1/sqrt(550)
    int i = E0 + half;
    for (; i + 2 < E1; i += 4) {
        int s0 = elist[i], s1 = elist[i + 2];
        const float* z0 = Z + (size_t)s0 * ZW;
        const float* z1 = Z + (size_t)s1 * ZW;
        float z0c = (l32 < 2) ? z0[hD + 64 + l32] : 0.f;
        float z1c = (l32 < 2) ? z1[hD + 64 + l32] : 0.f;
        float p0 = hd_a * z0[hD + l32] + hd_b * z0[hD + 32 + l32] + hd_c * z0c;
        float p1 = hd_a * z1[hD + l32] + hd_b * z1[hD + 32 + l32] + hd_c * z1c;
        float as0 = z0[134 + h], as1 = z1[134 + h];
        #pragma unroll
        for (int off = 16; off >= 1; off >>= 1) {
            p0 += __shfl_xor(p0, off, 32);
            p1 += __shfl_xor(p1, off, 32);
        }
        float al0 = (p0 + adv + as0) * isc;
        float al1 = (p1 + adv + as1) * isc;
        size_t v0b = (size_t)s0 * D1, v1b = (size_t)s1 * D1;
        float v0a = h1[v0b + l32], v0bb = h1[v0b + 32 + l32];
        float v0c = (l32 < 2) ? h1[v0b + 64 + l32] : 0.f;
        float v1a = h1[v1b + l32], v1bb = h1[v1b + 32 + l32];
        float v1c = (l32 < 2) ? h1[v1b + 64 + l32] : 0.f;
        float mp = fmaxf(al0, al1);
        float e0 = __expf(al0 - mp), e1 = __expf(al1 - mp);
        float lp = e0 + e1;
        float mnew = fmaxf(m, mp);
        float sc = __expf(m - mnew), sp = __expf(mp - mnew);
        lsum = lsum * sc + lp * sp;
        aa = aa * sc + (e0 * v0a + e1 * v1a) * sp;
        ab = ab * sc + (e0 * v0bb + e1 * v1bb) * sp;
        ac = ac * sc + (e0 * v0c + e1 * v1c) * sp;
        m = mnew;
    }
    for (; i < E1; i += 2) {
        int s = elist[i];
        const float* zr = Z + (size_t)s * ZW;
        float zc = (l32 < 2) ? zr[hD + 64 + l32] : 0.f;
        float p = hd_a * zr[hD + l32] + hd_b * zr[hD + 32 + l32] + hd_c * zc;
        float as_ = zr[134 + h];
        #pragma unroll
        for (int off = 16; off >= 1; off >>= 1) p += __shfl_xor(p, off, 32);
        float alpha = (p + adv + as_) * isc;
        size_t vb = (size_t)s * D1;
        float va = h1[vb + l32], vbb = h1[vb + 32 + l32];
        float vc = (l32 < 2) ? h1[vb + 64 + l32] : 0.f;
        float mnew = fmaxf(m, alpha);
        float sc = __expf(m - mnew);
        float pe = __expf(alpha - mnew);
        lsum = lsum * sc + pe;
        aa = aa * sc + pe * va;
        ab = ab * sc + pe * vbb;
        ac = ac * sc + pe * vc;
        m = mnew;
    }
    // merge halves (register shuffles across lane^32; -inf safe)
    float mO  = __shfl_xor(m, 32, 64);
    float lO  = __shfl_xor(lsum, 32, 64);
    float aaO = __shfl_xor(aa, 32, 64);
    float abO = __shfl_xor(ab, 32, 64);
    float acO = __shfl_xor(ac, 32, 64);
    float mnew = fmaxf(m, mO);
    float sS = (m  > -INFINITY) ? __expf(m  - mnew) : 0.f;
    float sO = (mO > -INFINITY) ? __expf(mO - mnew) : 0.f;
    lsum = lsum * sS + lO * sO;
    aa = aa * sS + aaO * sO;
    ab = ab * sS + abO * sO;
    ac = ac * sS + acO * sO;
    float inv = (lsum > 0.f) ? 1.f / lsum : 0.f;
    size_t ub = (size_t)n * KU;
    if (half == 0) {
        U[ub + hD + l32] = f2bf(aa * inv);
        if (l32 < 2) U[ub + hD + 64 + l32] = f2bf(ac * inv);
    } else {
        U[ub + hD + 32 + l32] = f2bf(ab * inv);
    }
    if (lane == 0) U[ub + 198 + h] = (lsum > 0.f) ? (unsigned short)0x3F80 : (unsigned short)0;
    if (h == 0) {
        if (half == 0) {
            U[ub + 132 + l32] = f2bf(hd_a);
            if (l32 < 2) U[ub + 132 + 64 + l32] = f2bf(hd_c);
            if (l32 == 2) U[ub + 223] = (unsigned short)0x3F80;   // const-1 col (bias)
        } else {
            U[ub + 132 + 32 + l32] = f2bf(hd_b);
        }
    } else if (half == 1 && l32 < 23) {
        U[ub + 200 + l32] = 0;                                    // zero pad 200..222
    }
}

// ---------------- MFMA GEMM 2: out = pairmax(U @ W2t^T); bias/flag folded into K ----------------
__global__ __launch_bounds__(256) void k_mm2(
        const unsigned short* __restrict__ A, const unsigned short* __restrict__ B,
        float* __restrict__ out, int N, int nRow, int slots) {
    __shared__ float ot[4][32][49];
    int s = xcd_slot(blockIdx.x, slots);
    if (s >= nRow * 12) return;
    int rowt = s / 12, g = s - rowt * 12;
    int wave = threadIdx.x >> 6, lane = threadIdx.x & 63;
    int lr = lane & 15, lk = lane >> 4;
    int rbase = rowt * 128 + wave * 32;
    int ar[2];
    #pragma unroll
    for (int mi = 0; mi < 2; mi++) {
        int r = rbase + mi * 16 + lr;
        ar[mi] = (r < N) ? r : (N - 1);
    }
    bfrag a[2][7];
    #pragma unroll
    for (int mi = 0; mi < 2; mi++)
        #pragma unroll
        for (int ks = 0; ks < 7; ks++)
            a[mi][ks] = *(const bfrag*)(A + (size_t)ar[mi] * KU + ks * 32 + lk * 8);
    f32x4 acc[2][6];
    #pragma unroll
    for (int mi = 0; mi < 2; mi++)
        #pragma unroll
        for (int ni = 0; ni < 6; ni++) acc[mi][ni] = (f32x4){0.f, 0.f, 0.f, 0.f};
    #pragma unroll
    for (int ks = 0; ks < 7; ks++) {
        bfrag b[6];
        #pragma unroll
        for (int ni = 0; ni < 6; ni++)
            b[ni] = *(const bfrag*)(B + (size_t)(g * 7 + ks) * 3072 + lk * 768 + (ni * 16 + lr) * 8);
        #pragma unroll
        for (int mi = 0; mi < 2; mi++)
            #pragma unroll
            for (int ni = 0; ni < 6; ni++)
                acc[mi][ni] = __builtin_amdgcn_mfma_f32_16x16x32_bf16(a[mi][ks], b[ni], acc[mi][ni], 0, 0, 0);
    }
    // pair-max into per-wave LDS tile
    #pragma unroll
    for (int mi = 0; mi < 2; mi++) {
        #pragma unroll
        for (int ni = 0; ni < 6; ni++) {
            #pragma unroll
            for (int r = 0; r < 4; r++) {
                float val = acc[mi][ni][r];
                float oth = __shfl_xor(val, 1, 64);
                if (!(lane & 1))
                    ot[wave][mi * 16 + lk * 4 + r][ni * 8 + (lr >> 1)] = fmaxf(val, oth);
            }
        }
    }
    __syncthreads();
    // coalesced write: 32 rows x 48 cols per wave
    int colb = g * 48;
    #pragma unroll
    for (int i = 0; i < 24; i++) {
        int t = i * 64 + lane;
        int r32 = t / 48, pos = t - r32 * 48;
        int row = rbase + r32;
        int col = colb + pos;
        if (row < N && col < C2)
            out[(size_t)row * C2 + col] = ot[wave][r32][pos];
    }
}

// ---------------- launcher ----------------
extern "C" void kernel_launch(void* const* d_in, const int* in_sizes, int n_in,
                              void* d_out, int out_size, void* d_ws, size_t ws_size,
                              hipStream_t stream) {
    const float* x  = (const float*)d_in[0];
    const int*   ei = (const int*)d_in[1];
    int N = in_sizes[0] / IN1;
    int E = in_sizes[1] / 2;
    const int* src = ei;
    const int* dst = ei + E;

    const float *Wq1 = (const float*)d_in[2],  *bq1 = (const float*)d_in[3];
    const float *Wk1 = (const float*)d_in[4],  *bk1 = (const float*)d_in[5];
    const float *Wv1 = (const float*)d_in[6],  *bv1 = (const float*)d_in[7];
    const float *Ws1 = (const float*)d_in[8],  *bs1 = (const float*)d_in[9];
    const float *Wq2 = (const float*)d_in[10], *bq2 = (const float*)d_in[11];
    const float *Wk2 = (const float*)d_in[12], *bk2 = (const float*)d_in[13];
    const float *Wv2 = (const float*)d_in[14], *bv2 = (const float*)d_in[15];
    const float *Ws2 = (const float*)d_in[16], *bs2 = (const float*)d_in[17];

    char* w = (char*)d_ws;
    size_t off = 0;
    auto take = [&](size_t bytes) { size_t o = off; off = (off + bytes + 255) & ~(size_t)255; return o; };

    size_t proj_off = take((size_t)N * PROJW * 4);
    float* proj = (float*)(w + proj_off);
    // aliased into proj region AFTER conv1 consumes proj:
    float* Z = proj;                                                       // N*144*4 = 11.52 MB
    unsigned short* U = (unsigned short*)(w + proj_off + (size_t)N * ZW * 4);  // N*224*2 = 8.96 MB
    float* h1   = (float*)(w + take((size_t)N * D1 * 4));
    unsigned short* h1b = (unsigned short*)(w + take((size_t)N * KZ * 2));
    float* cc   = (float*)(w + take(2 * 4));
    unsigned short* GBt = (unsigned short*)(w + take((size_t)24 * 96 * 8 * 2));
    unsigned short* Wt1 = (unsigned short*)(w + take((size_t)96 * 96 * 8 * 2));
    float* bcat = (float*)(w + take(PROJW * 4));
    unsigned short* W2t = (unsigned short*)(w + take((size_t)336 * 96 * 8 * 2));
    int* cnt   = (int*)(w + take((size_t)N * 4));
    int* roff  = (int*)(w + take((size_t)(N + 1) * 4));
    int* pos   = (int*)(w + take((size_t)N * 4));
    int* elist = (int*)(w + take((size_t)E * 4));

    int histBlocks = (E + 255) / 256;
    int nRow1 = (N + 127) / 128;
    int tot1  = nRow1 * 3;
    int slots1 = (tot1 + 7) / 8;
    int nRowZ = (N + 63) / 64;
    int totZ  = nRowZ * 2;
    int slotsZ = (totZ + 7) / 8;
    int nRow2 = (N + 127) / 128;
    int tot2  = nRow2 * 12;
    int slots2 = (tot2 + 7) / 8;

    // 1) zero hist counters
    hipMemsetAsync(cnt, 0, (size_t)N * sizeof(int), stream);

    // 2) mega prep: hist | Wt1+bcat | W2t | GBt+cc (all independent)
    k_mega<<<histBlocks + 96 + 336 + 2245, 256, 0, stream>>>(
        dst, E, cnt, histBlocks,
        Wq1, bq1, Wk1, bk1, Wv1, bv1, Ws1, bs1, Wt1, bcat,
        Wv2, bv2, Ws2, bs2, W2t,
        Wq2, bq2, Wk2, bk2, GBt, cc);

    // 3) scan
    k_scan<<<1, 1024, 0, stream>>>(cnt, roff, pos, N);

    // 4) fused CSR fill | mm1 (independent)
    k_fillmm1<<<histBlocks + slots1 * 8, 256, 0, stream>>>(
        src, dst, E, pos, elist, histBlocks,
        x, Wt1, bcat, proj, N, nRow1, slots1);

    // 5) conv1 edge phase
    k_conv1<<<N, 128, 0, stream>>>(proj, roff, elist, h1, h1b, N);

    // 6) z-GEMM
    k_mmz<<<slotsZ * 8, 256, 0, stream>>>(h1b, GBt, Z, N, nRowZ, slotsZ);

    // 7) conv2 edge phase
    k_conv2<<<N, 128, 0, stream>>>(h1, Z, cc, roff, elist, U, N);

    // 8) final fused GEMM + pair-max epilogue
    k_mm2<<<slots2 * 8, 256, 0, stream>>>(U, W2t, (float*)d_out, N, nRow2, slots2);
}

// Round 17
// 162.199 us; speedup vs baseline: 1.0916x; 1.0040x over previous
//
#include <hip/hip_runtime.h>
#include <math.h>

#define HEADS 2
#define C1    33
#define C2    550
#define D1    66     // HEADS*C1
#define D2    1100   // HEADS*C2
#define IN1   256
#define PROJW 288    // padded q|k|v|s width (264 -> 288 = 3*96)
#define KU    224    // padded U width (198 -> 224 = 7*32)
#define KZ    96     // padded K for z-GEMM (66 -> 96)
#define ZW    144    // Z row stride (136 used -> 144)

typedef __attribute__((ext_vector_type(8))) short bfrag;   // 8 bf16 (bits in short)
typedef __attribute__((ext_vector_type(4))) float f32x4;

__device__ inline unsigned short f2bf(float f) {
    unsigned int u = __float_as_uint(f);
    u += 0x7FFFu + ((u >> 16) & 1u);
    return (unsigned short)(u >> 16);
}

// XCD-aware swizzle: blocks with equal bid%8 (same XCD) get contiguous work
// slots, so all col-groups of a row-tile run on one XCD and share its L2.
__device__ inline int xcd_slot(int bid, int slots) {
    return (bid >> 3) + (bid & 7) * slots;
}

// ================= mega prep: hist | Wt1 | W2t | GBt/cc (independent jobs) ==============
__global__ __launch_bounds__(256) void k_mega(
        const int* __restrict__ dst, int E, int* __restrict__ cnt, int histBlocks,
        const float* __restrict__ Wq1, const float* __restrict__ bq1,
        const float* __restrict__ Wk1, const float* __restrict__ bk1,
        const float* __restrict__ Wv1, const float* __restrict__ bv1,
        const float* __restrict__ Ws1, const float* __restrict__ bs1,
        unsigned short* __restrict__ Wt1, float* __restrict__ bcat,
        const float* __restrict__ Wv2, const float* __restrict__ bv2,
        const float* __restrict__ Ws2, const float* __restrict__ bs2,
        unsigned short* __restrict__ W2t,
        const float* __restrict__ Wq2, const float* __restrict__ bq2,
        const float* __restrict__ Wk2, const float* __restrict__ bk2,
        unsigned short* __restrict__ GBt, float* __restrict__ cc) {
    int bid = blockIdx.x;
    int tid = threadIdx.x;
    if (bid < histBlocks) {
        // -------- hist --------
        int e = bid * 256 + tid;
        if (e < E) atomicAdd(&cnt[dst[e]], 1);
        return;
    }
    bid -= histBlocks;
    if (bid < 96) {
        // -------- Wt1 fragment-order [3][8][4][96][8] + bcat --------
        if (tid >= 96) return;
        int lk = bid & 3, t = bid >> 2;
        int ks = t & 7, g = t >> 3;
        int col = tid;
        int c = g * 96 + col;
        int k0 = ks * 32 + lk * 8;
        short vals[8];
        float bia = 0.f;
        if (c < 4 * D1) {
            int m = c / D1, j = c % D1;
            const float* W; const float* B;
            switch (m) {
                case 0: W = Wq1; B = bq1; break;
                case 1: W = Wk1; B = bk1; break;
                case 2: W = Wv1; B = bv1; break;
                default: W = Ws1; B = bs1; break;
            }
            #pragma unroll
            for (int e = 0; e < 8; e++) vals[e] = (short)f2bf(W[(size_t)(k0 + e) * D1 + j]);
            bia = B[j];
        } else {
            #pragma unroll
            for (int e = 0; e < 8; e++) vals[e] = 0;
        }
        *(bfrag*)&Wt1[((size_t)bid * 96 + col) * 8] = *(bfrag*)vals;
        if (ks == 0 && lk == 0) bcat[c] = bia;
        return;
    }
    bid -= 96;
    if (bid < 336) {
        // -------- W2t fragment-order [12][7][4][96][8]; bias rows folded --------
        if (tid >= 96) return;
        int lk = bid & 3, t = bid >> 2;
        int ks = t % 7, g = t / 7;
        int col = tid;
        int c = g * 96 + col;
        int k0 = ks * 32 + lk * 8;
        short vals[8];
        #pragma unroll
        for (int e = 0; e < 8; e++) {
            int k = k0 + e;
            float val = 0.f;
            if (c < D2) {
                if (c < C2) {
                    if (k < 66) val = Wv2[(size_t)k * D2 + c];
                    else if (k >= 132 && k < 198) val = Ws2[(size_t)(k - 132) * D2 + c];
                    else if (k == 198) val = bv2[c];
                    else if (k == 223) val = bs2[c];
                } else {
                    if (k >= 66 && k < 132) val = Wv2[(size_t)(k - 66) * D2 + c];
                    else if (k >= 132 && k < 198) val = Ws2[(size_t)(k - 132) * D2 + c];
                    else if (k == 199) val = bv2[c];
                    else if (k == 223) val = bs2[c];
                }
            }
            vals[e] = (short)f2bf(val);
        }
        *(bfrag*)&W2t[((size_t)bid * 96 + col) * 8] = *(bfrag*)vals;
        return;
    }
    bid -= 336;
    {
        // -------- precomp dots -> GBt fragment slots + cc --------
        int wave = tid >> 6, lane = tid & 63;
        int j = bid * 4 + wave;
        if (j >= 8978) return;
        const float *u, *v;
        int h = 0, a = 0, b = 0;
        if (j < 8976) {
            h = j / 4488;
            int r = j % 4488;
            a = r / 68; b = r % 68;
            if (b < 66)      { u = Wq2 + (size_t)a * D2 + h * C2; v = Wk2 + (size_t)b * D2 + h * C2; }
            else if (b == 66){ u = Wq2 + (size_t)a * D2 + h * C2; v = bk2 + h * C2; }
            else             { u = Wk2 + (size_t)a * D2 + h * C2; v = bq2 + h * C2; }
        } else {
            h = j - 8976;
            u = bq2 + h * C2; v = bk2 + h * C2;
        }
        float acc = 0.f;
        for (int c = lane; c < C2; c += 64) acc += u[c] * v[c];
        #pragma unroll
        for (int off = 32; off >= 1; off >>= 1) acc += __shfl_xor(acc, off, 64);
        if (lane == 0) {
            if (j < 8976) {
                int r, k;
                if (b < 66)      { r = h * 66 + a; k = b; }
                else if (b == 66){ r = 132 + h;    k = a; }
                else             { r = 134 + h;    k = a; }
                int g = r / 96, cm = r % 96;
                int ks2 = k >> 5, rem = k & 31, lk2 = rem >> 3, e = rem & 7;
                GBt[(((size_t)(g * 3 + ks2) * 4 + lk2) * 96 + cm) * 8 + e] = f2bf(acc);
            } else {
                cc[h] = acc;
            }
        }
    }
}

// ---------------- scan ----------------
__global__ void k_scan(const int* __restrict__ cnt, int* __restrict__ roff,
                       int* __restrict__ pos, int N) {
    __shared__ int wsum[16];
    __shared__ int carry_s;
    int tid = threadIdx.x, wid = tid >> 6, lane = tid & 63;
    if (tid == 0) { carry_s = 0; roff[0] = 0; }
    __syncthreads();
    for (int base = 0; base < N; base += 1024) {
        int i = base + tid;
        int v = (i < N) ? cnt[i] : 0;
        int x = v;
        #pragma unroll
        for (int s = 1; s < 64; s <<= 1) {
            int t = __shfl_up(x, s, 64);
            if (lane >= s) x += t;
        }
        if (lane == 63) wsum[wid] = x;
        __syncthreads();
        if (tid < 16) {
            int y = wsum[tid];
            #pragma unroll
            for (int s = 1; s < 16; s <<= 1) {
                int t = __shfl_up(y, s, 16);
                if (tid >= s) y += t;
            }
            wsum[tid] = y;
        }
        __syncthreads();
        int carry = carry_s;
        int incl = carry + (wid ? wsum[wid - 1] : 0) + x;
        if (i < N) { roff[i + 1] = incl; pos[i] = incl - v; }
        __syncthreads();
        if (tid == 0) carry_s = carry + wsum[15];
        __syncthreads();
    }
}

// ================= fused: CSR fill | MFMA GEMM 1 (64-row tiles) ==============
__global__ __launch_bounds__(256) void k_fillmm1(
        const int* __restrict__ src, const int* __restrict__ dst, int E,
        int* __restrict__ pos, int* __restrict__ elist, int fillBlocks,
        const float* __restrict__ X, const unsigned short* __restrict__ B,
        const float* __restrict__ bias, float* __restrict__ proj, int N,
        int nRow, int slots) {
    int bid = blockIdx.x;
    int tid = threadIdx.x;
    if (bid < fillBlocks) {
        int e = bid * 256 + tid;
        if (e < E) {
            int slot = atomicAdd(&pos[dst[e]], 1);
            elist[slot] = src[e];
        }
        return;
    }
    bid -= fillBlocks;
    // -------- mm1: proj = x @ W^T + bcat; wave-tile 16 rows x 96 cols --------
    int s = xcd_slot(bid, slots);
    if (s >= nRow * 3) return;
    int rowt = s / 3, g = s - rowt * 3;
    int cbase = g * 96;
    int wave = tid >> 6, lane = tid & 63;
    int lr = lane & 15, lk = lane >> 4;
    int rbase = rowt * 64 + wave * 16;
    int r0 = rbase + lr;
    int ar = (r0 < N) ? r0 : (N - 1);
    bfrag a[8];
    #pragma unroll
    for (int ks = 0; ks < 8; ks++) {
        const float* p = X + (size_t)ar * IN1 + ks * 32 + lk * 8;
        float4 v0 = *(const float4*)p;
        float4 v1 = *(const float4*)(p + 4);
        bfrag r;
        r[0] = (short)f2bf(v0.x); r[1] = (short)f2bf(v0.y);
        r[2] = (short)f2bf(v0.z); r[3] = (short)f2bf(v0.w);
        r[4] = (short)f2bf(v1.x); r[5] = (short)f2bf(v1.y);
        r[6] = (short)f2bf(v1.z); r[7] = (short)f2bf(v1.w);
        a[ks] = r;
    }
    f32x4 acc[6];
    #pragma unroll
    for (int ni = 0; ni < 6; ni++) acc[ni] = (f32x4){0.f, 0.f, 0.f, 0.f};
    #pragma unroll
    for (int ks = 0; ks < 8; ks++) {
        bfrag b[6];
        #pragma unroll
        for (int ni = 0; ni < 6; ni++)
            b[ni] = *(const bfrag*)(B + (size_t)(g * 8 + ks) * 3072 + lk * 768 + (ni * 16 + lr) * 8);
        #pragma unroll
        for (int ni = 0; ni < 6; ni++)
            acc[ni] = __builtin_amdgcn_mfma_f32_16x16x32_bf16(a[ks], b[ni], acc[ni], 0, 0, 0);
    }
    #pragma unroll
    for (int ni = 0; ni < 6; ni++) {
        int col = cbase + ni * 16 + lr;
        float bia = bias[col];
        #pragma unroll
        for (int r = 0; r < 4; r++) {
            int row = rbase + lk * 4 + r;
            if (row < N) proj[(size_t)row * PROJW + col] = acc[ni][r] + bia;
        }
    }
}

// ---------------- conv1: wave=head, half-wave per edge (dims via l32) ----------------
__global__ __launch_bounds__(128) void k_conv1(
        const float* __restrict__ proj, const int* __restrict__ roff,
        const int* __restrict__ elist, float* __restrict__ h1,
        unsigned short* __restrict__ h1b, int N) {
    int n = blockIdx.x;
    int h = threadIdx.x >> 6;
    int lane = threadIdx.x & 63;
    int half = lane >> 5, l32 = lane & 31;
    size_t pb = (size_t)n * PROJW;
    int hc = h * C1;
    float q_a = proj[pb + hc + l32];                      // dims 0..31
    float q_b = (l32 == 0) ? proj[pb + hc + 32] : 0.f;    // dim 32
    int E0 = roff[n], E1 = roff[n + 1];
    float m = -INFINITY, lsum = 0.f, aca = 0.f, acb = 0.f;
    const float isc = 0.17407765595569785f;  // 1/sqrt(33)
    int i = E0 + half;
    for (; i + 2 < E1; i += 4) {
        int s0 = elist[i], s1 = elist[i + 2];
        size_t b0 = (size_t)s0 * PROJW, b1 = (size_t)s1 * PROJW;
        float k0a = proj[b0 + 66 + hc + l32];
        float k0b = (l32 == 0) ? proj[b0 + 66 + hc + 32] : 0.f;
        float k1a = proj[b1 + 66 + hc + l32];
        float k1b = (l32 == 0) ? proj[b1 + 66 + hc + 32] : 0.f;
        float v0a = proj[b0 + 132 + hc + l32];
        float v0b = (l32 == 0) ? proj[b0 + 132 + hc + 32] : 0.f;
        float v1a = proj[b1 + 132 + hc + l32];
        float v1b = (l32 == 0) ? proj[b1 + 132 + hc + 32] : 0.f;
        float p0 = q_a * k0a + q_b * k0b;
        float p1 = q_a * k1a + q_b * k1b;
        #pragma unroll
        for (int off = 16; off >= 1; off >>= 1) {
            p0 += __shfl_xor(p0, off, 32);
            p1 += __shfl_xor(p1, off, 32);
        }
        float a0 = p0 * isc, a1 = p1 * isc;
        float mp = fmaxf(a0, a1);
        float e0 = __expf(a0 - mp), e1 = __expf(a1 - mp);
        float lp = e0 + e1;
        float apa = e0 * v0a + e1 * v1a;
        float apb = e0 * v0b + e1 * v1b;
        float mnew = fmaxf(m, mp);
        float sc = __expf(m - mnew), sp = __expf(mp - mnew);
        lsum = lsum * sc + lp * sp;
        aca = aca * sc + apa * sp;
        acb = acb * sc + apb * sp;
        m = mnew;
    }
    for (; i < E1; i += 2) {
        int s = elist[i];
        size_t sb = (size_t)s * PROJW;
        float ka = proj[sb + 66 + hc + l32];
        float kb = (l32 == 0) ? proj[sb + 66 + hc + 32] : 0.f;
        float va = proj[sb + 132 + hc + l32];
        float vb = (l32 == 0) ? proj[sb + 132 + hc + 32] : 0.f;
        float p = q_a * ka + q_b * kb;
        #pragma unroll
        for (int off = 16; off >= 1; off >>= 1) p += __shfl_xor(p, off, 32);
        float alpha = p * isc;
        float mnew = fmaxf(m, alpha);
        float sc = __expf(m - mnew);
        float pe = __expf(alpha - mnew);
        lsum = lsum * sc + pe;
        aca = aca * sc + pe * va;
        acb = acb * sc + pe * vb;
        m = mnew;
    }
    // merge the two halves (register shuffles across lane^32; -inf safe)
    float mO  = __shfl_xor(m, 32, 64);
    float lO  = __shfl_xor(lsum, 32, 64);
    float aaO = __shfl_xor(aca, 32, 64);
    float abO = __shfl_xor(acb, 32, 64);
    float mnew = fmaxf(m, mO);
    float sS = (m  > -INFINITY) ? __expf(m  - mnew) : 0.f;
    float sO = (mO > -INFINITY) ? __expf(mO - mnew) : 0.f;
    lsum = lsum * sS + lO * sO;
    aca  = aca * sS + aaO * sO;
    acb  = acb * sS + abO * sO;
    float inv = (lsum > 0.f) ? 1.f / lsum : 0.f;
    if (half == 0) {
        float s1a = proj[pb + 198 + hc + l32];
        float val = aca * inv + s1a;
        h1[(size_t)n * D1 + hc + l32] = val;
        h1b[(size_t)n * KZ + hc + l32] = f2bf(val);
        if (l32 == 0) {
            float s1b = proj[pb + 198 + hc + 32];
            float valb = acb * inv + s1b;
            h1[(size_t)n * D1 + hc + 32] = valb;
            h1b[(size_t)n * KZ + hc + 32] = f2bf(valb);
        }
    } else if (h == 1 && l32 < 30) {
        h1b[(size_t)n * KZ + D1 + l32] = 0;   // zero pad cols 66..95
    }
}

// ---------------- MFMA GEMM z: Z[N][144] = h1b[N][96] @ GBt^T (cols 0..135 valid) ----------------
__global__ __launch_bounds__(256) void k_mmz(
        const unsigned short* __restrict__ A, const unsigned short* __restrict__ B,
        float* __restrict__ Z, int N, int nRow, int slots) {
    int s = xcd_slot(blockIdx.x, slots);
    if (s >= nRow * 2) return;
    int rowt = s >> 1, g = s & 1;
    int wave = threadIdx.x >> 6, lane = threadIdx.x & 63;
    int lr = lane & 15, lk = lane >> 4;
    int rbase = rowt * 64 + (wave >> 1) * 32;
    int ch = (wave & 1) * 48;
    int cbase = g * 96 + ch;
    f32x4 acc[2][3];
    #pragma unroll
    for (int i = 0; i < 2; i++)
        #pragma unroll
        for (int j = 0; j < 3; j++) acc[i][j] = (f32x4){0.f, 0.f, 0.f, 0.f};
    int ar[2];
    #pragma unroll
    for (int mi = 0; mi < 2; mi++) {
        int r = rbase + mi * 16 + lr;
        ar[mi] = (r < N) ? r : (N - 1);
    }
    #pragma unroll
    for (int ks = 0; ks < 3; ks++) {
        bfrag a[2], b[3];
        #pragma unroll
        for (int mi = 0; mi < 2; mi++)
            a[mi] = *(const bfrag*)(A + (size_t)ar[mi] * KZ + ks * 32 + lk * 8);
        #pragma unroll
        for (int ni = 0; ni < 3; ni++)
            b[ni] = *(const bfrag*)(B + (size_t)(g * 3 + ks) * 3072 + lk * 768 + (ch + ni * 16 + lr) * 8);
        #pragma unroll
        for (int mi = 0; mi < 2; mi++)
            #pragma unroll
            for (int ni = 0; ni < 3; ni++)
                acc[mi][ni] = __builtin_amdgcn_mfma_f32_16x16x32_bf16(a[mi], b[ni], acc[mi][ni], 0, 0, 0);
    }
    #pragma unroll
    for (int mi = 0; mi < 2; mi++) {
        #pragma unroll
        for (int ni = 0; ni < 3; ni++) {
            int col = cbase + ni * 16 + lr;
            if (col >= 136) continue;
            #pragma unroll
            for (int r = 0; r < 4; r++) {
                int row = rbase + mi * 16 + lk * 4 + r;
                if (row < N) Z[(size_t)row * ZW + col] = acc[mi][ni][r];
            }
        }
    }
}

// ---------------- conv2: wave=head, half-wave per edge (dims via l32) ----------------
__global__ __launch_bounds__(128) void k_conv2(
        const float* __restrict__ h1, const float* __restrict__ Z,
        const float* __restrict__ cc, const int* __restrict__ roff,
        const int* __restrict__ elist, unsigned short* __restrict__ U, int N) {
    int n = blockIdx.x;
    int h = threadIdx.x >> 6;
    int lane = threadIdx.x & 63;
    int half = lane >> 5, l32 = lane & 31;
    int hD = h * D1;
    size_t nb = (size_t)n * D1;
    float hd_a = h1[nb + l32];                       // dims 0..31
    float hd_b = h1[nb + 32 + l32];                  // dims 32..63
    float hd_c = (l32 < 2) ? h1[nb + 64 + l32] : 0.f; // dims 64,65
    float adv = Z[(size_t)n * ZW + 132 + h] + cc[h];
    int E0 = roff[n], E1 = roff[n + 1];
    float m = -INFINITY, lsum = 0.f, aa = 0.f, ab = 0.f, ac = 0.f;
    const float isc = 0.04264014327112209f;  // 1/sqrt(550)
    int i = E0 + half;
    for (; i + 2 < E1; i += 4) {
        int s0 = elist[i], s1 = elist[i + 2];
        const float* z0 = Z + (size_t)s0 * ZW;
        const float* z1 = Z + (size_t)s1 * ZW;
        float z0c = (l32 < 2) ? z0[hD + 64 + l32] : 0.f;
        float z1c = (l32 < 2) ? z1[hD + 64 + l32] : 0.f;
        float p0 = hd_a * z0[hD + l32] + hd_b * z0[hD + 32 + l32] + hd_c * z0c;
        float p1 = hd_a * z1[hD + l32] + hd_b * z1[hD + 32 + l32] + hd_c * z1c;
        float as0 = z0[134 + h], as1 = z1[134 + h];
        #pragma unroll
        for (int off = 16; off >= 1; off >>= 1) {
            p0 += __shfl_xor(p0, off, 32);
            p1 += __shfl_xor(p1, off, 32);
        }
        float al0 = (p0 + adv + as0) * isc;
        float al1 = (p1 + adv + as1) * isc;
        size_t v0b = (size_t)s0 * D1, v1b = (size_t)s1 * D1;
        float v0a = h1[v0b + l32], v0bb = h1[v0b + 32 + l32];
        float v0c = (l32 < 2) ? h1[v0b + 64 + l32] : 0.f;
        float v1a = h1[v1b + l32], v1bb = h1[v1b + 32 + l32];
        float v1c = (l32 < 2) ? h1[v1b + 64 + l32] : 0.f;
        float mp = fmaxf(al0, al1);
        float e0 = __expf(al0 - mp), e1 = __expf(al1 - mp);
        float lp = e0 + e1;
        float mnew = fmaxf(m, mp);
        float sc = __expf(m - mnew), sp = __expf(mp - mnew);
        lsum = lsum * sc + lp * sp;
        aa = aa * sc + (e0 * v0a + e1 * v1a) * sp;
        ab = ab * sc + (e0 * v0bb + e1 * v1bb) * sp;
        ac = ac * sc + (e0 * v0c + e1 * v1c) * sp;
        m = mnew;
    }
    for (; i < E1; i += 2) {
        int s = elist[i];
        const float* zr = Z + (size_t)s * ZW;
        float zc = (l32 < 2) ? zr[hD + 64 + l32] : 0.f;
        float p = hd_a * zr[hD + l32] + hd_b * zr[hD + 32 + l32] + hd_c * zc;
        float as_ = zr[134 + h];
        #pragma unroll
        for (int off = 16; off >= 1; off >>= 1) p += __shfl_xor(p, off, 32);
        float alpha = (p + adv + as_) * isc;
        size_t vb = (size_t)s * D1;
        float va = h1[vb + l32], vbb = h1[vb + 32 + l32];
        float vc = (l32 < 2) ? h1[vb + 64 + l32] : 0.f;
        float mnew = fmaxf(m, alpha);
        float sc = __expf(m - mnew);
        float pe = __expf(alpha - mnew);
        lsum = lsum * sc + pe;
        aa = aa * sc + pe * va;
        ab = ab * sc + pe * vbb;
        ac = ac * sc + pe * vc;
        m = mnew;
    }
    // merge halves (register shuffles across lane^32; -inf safe)
    float mO  = __shfl_xor(m, 32, 64);
    float lO  = __shfl_xor(lsum, 32, 64);
    float aaO = __shfl_xor(aa, 32, 64);
    float abO = __shfl_xor(ab, 32, 64);
    float acO = __shfl_xor(ac, 32, 64);
    float mnew = fmaxf(m, mO);
    float sS = (m  > -INFINITY) ? __expf(m  - mnew) : 0.f;
    float sO = (mO > -INFINITY) ? __expf(mO - mnew) : 0.f;
    lsum = lsum * sS + lO * sO;
    aa = aa * sS + aaO * sO;
    ab = ab * sS + abO * sO;
    ac = ac * sS + acO * sO;
    float inv = (lsum > 0.f) ? 1.f / lsum : 0.f;
    size_t ub = (size_t)n * KU;
    if (half == 0) {
        U[ub + hD + l32] = f2bf(aa * inv);
        if (l32 < 2) U[ub + hD + 64 + l32] = f2bf(ac * inv);
    } else {
        U[ub + hD + 32 + l32] = f2bf(ab * inv);
    }
    if (lane == 0) U[ub + 198 + h] = (lsum > 0.f) ? (unsigned short)0x3F80 : (unsigned short)0;
    if (h == 0) {
        if (half == 0) {
            U[ub + 132 + l32] = f2bf(hd_a);
            if (l32 < 2) U[ub + 132 + 64 + l32] = f2bf(hd_c);
            if (l32 == 2) U[ub + 223] = (unsigned short)0x3F80;   // const-1 col (bias)
        } else {
            U[ub + 132 + 32 + l32] = f2bf(hd_b);
        }
    } else if (half == 1 && l32 < 23) {
        U[ub + 200 + l32] = 0;                                    // zero pad 200..222
    }
}

// ---------------- MFMA GEMM 2 (64-row tiles): out = pairmax(U @ W2t^T) ----------------
__global__ __launch_bounds__(256) void k_mm2(
        const unsigned short* __restrict__ A, const unsigned short* __restrict__ B,
        float* __restrict__ out, int N, int nRow, int slots) {
    __shared__ float ot[4][16][49];
    int s = xcd_slot(blockIdx.x, slots);
    if (s >= nRow * 12) return;
    int rowt = s / 12, g = s - rowt * 12;
    int wave = threadIdx.x >> 6, lane = threadIdx.x & 63;
    int lr = lane & 15, lk = lane >> 4;
    int rbase = rowt * 64 + wave * 16;
    int r0 = rbase + lr;
    int ar = (r0 < N) ? r0 : (N - 1);
    bfrag a[7];
    #pragma unroll
    for (int ks = 0; ks < 7; ks++)
        a[ks] = *(const bfrag*)(A + (size_t)ar * KU + ks * 32 + lk * 8);
    f32x4 acc[6];
    #pragma unroll
    for (int ni = 0; ni < 6; ni++) acc[ni] = (f32x4){0.f, 0.f, 0.f, 0.f};
    #pragma unroll
    for (int ks = 0; ks < 7; ks++) {
        bfrag b[6];
        #pragma unroll
        for (int ni = 0; ni < 6; ni++)
            b[ni] = *(const bfrag*)(B + (size_t)(g * 7 + ks) * 3072 + lk * 768 + (ni * 16 + lr) * 8);
        #pragma unroll
        for (int ni = 0; ni < 6; ni++)
            acc[ni] = __builtin_amdgcn_mfma_f32_16x16x32_bf16(a[ks], b[ni], acc[ni], 0, 0, 0);
    }
    // pair-max into per-wave LDS tile
    #pragma unroll
    for (int ni = 0; ni < 6; ni++) {
        #pragma unroll
        for (int r = 0; r < 4; r++) {
            float val = acc[ni][r];
            float oth = __shfl_xor(val, 1, 64);
            if (!(lane & 1))
                ot[wave][lk * 4 + r][ni * 8 + (lr >> 1)] = fmaxf(val, oth);
        }
    }
    __syncthreads();
    // coalesced write: 16 rows x 48 cols per wave
    int colb = g * 48;
    #pragma unroll
    for (int i = 0; i < 12; i++) {
        int t = i * 64 + lane;
        int r16 = t / 48, pos = t - r16 * 48;
        int row = rbase + r16;
        int col = colb + pos;
        if (row < N && col < C2)
            out[(size_t)row * C2 + col] = ot[wave][r16][pos];
    }
}

// ---------------- launcher ----------------
extern "C" void kernel_launch(void* const* d_in, const int* in_sizes, int n_in,
                              void* d_out, int out_size, void* d_ws, size_t ws_size,
                              hipStream_t stream) {
    const float* x  = (const float*)d_in[0];
    const int*   ei = (const int*)d_in[1];
    int N = in_sizes[0] / IN1;
    int E = in_sizes[1] / 2;
    const int* src = ei;
    const int* dst = ei + E;

    const float *Wq1 = (const float*)d_in[2],  *bq1 = (const float*)d_in[3];
    const float *Wk1 = (const float*)d_in[4],  *bk1 = (const float*)d_in[5];
    const float *Wv1 = (const float*)d_in[6],  *bv1 = (const float*)d_in[7];
    const float *Ws1 = (const float*)d_in[8],  *bs1 = (const float*)d_in[9];
    const float *Wq2 = (const float*)d_in[10], *bq2 = (const float*)d_in[11];
    const float *Wk2 = (const float*)d_in[12], *bk2 = (const float*)d_in[13];
    const float *Wv2 = (const float*)d_in[14], *bv2 = (const float*)d_in[15];
    const float *Ws2 = (const float*)d_in[16], *bs2 = (const float*)d_in[17];

    char* w = (char*)d_ws;
    size_t off = 0;
    auto take = [&](size_t bytes) { size_t o = off; off = (off + bytes + 255) & ~(size_t)255; return o; };

    size_t proj_off = take((size_t)N * PROJW * 4);
    float* proj = (float*)(w + proj_off);
    // aliased into proj region AFTER conv1 consumes proj:
    float* Z = proj;                                                       // N*144*4 = 11.52 MB
    unsigned short* U = (unsigned short*)(w + proj_off + (size_t)N * ZW * 4);  // N*224*2 = 8.96 MB
    float* h1   = (float*)(w + take((size_t)N * D1 * 4));
    unsigned short* h1b = (unsigned short*)(w + take((size_t)N * KZ * 2));
    float* cc   = (float*)(w + take(2 * 4));
    unsigned short* GBt = (unsigned short*)(w + take((size_t)24 * 96 * 8 * 2));
    unsigned short* Wt1 = (unsigned short*)(w + take((size_t)96 * 96 * 8 * 2));
    float* bcat = (float*)(w + take(PROJW * 4));
    unsigned short* W2t = (unsigned short*)(w + take((size_t)336 * 96 * 8 * 2));
    int* cnt   = (int*)(w + take((size_t)N * 4));
    int* roff  = (int*)(w + take((size_t)(N + 1) * 4));
    int* pos   = (int*)(w + take((size_t)N * 4));
    int* elist = (int*)(w + take((size_t)E * 4));

    int histBlocks = (E + 255) / 256;
    int nRow1 = (N + 63) / 64;            // mm1 row tiles (64)
    int tot1  = nRow1 * 3;
    int slots1 = (tot1 + 7) / 8;
    int nRowZ = (N + 63) / 64;
    int totZ  = nRowZ * 2;
    int slotsZ = (totZ + 7) / 8;
    int nRow2 = (N + 63) / 64;            // mm2 row tiles (64)
    int tot2  = nRow2 * 12;
    int slots2 = (tot2 + 7) / 8;

    // 1) zero hist counters
    hipMemsetAsync(cnt, 0, (size_t)N * sizeof(int), stream);

    // 2) mega prep: hist | Wt1+bcat | W2t | GBt+cc (all independent)
    k_mega<<<histBlocks + 96 + 336 + 2245, 256, 0, stream>>>(
        dst, E, cnt, histBlocks,
        Wq1, bq1, Wk1, bk1, Wv1, bv1, Ws1, bs1, Wt1, bcat,
        Wv2, bv2, Ws2, bs2, W2t,
        Wq2, bq2, Wk2, bk2, GBt, cc);

    // 3) scan
    k_scan<<<1, 1024, 0, stream>>>(cnt, roff, pos, N);

    // 4) fused CSR fill | mm1 (independent)
    k_fillmm1<<<histBlocks + slots1 * 8, 256, 0, stream>>>(
        src, dst, E, pos, elist, histBlocks,
        x, Wt1, bcat, proj, N, nRow1, slots1);

    // 5) conv1 edge phase
    k_conv1<<<N, 128, 0, stream>>>(proj, roff, elist, h1, h1b, N);

    // 6) z-GEMM
    k_mmz<<<slotsZ * 8, 256, 0, stream>>>(h1b, GBt, Z, N, nRowZ, slotsZ);

    // 7) conv2 edge phase
    k_conv2<<<N, 128, 0, stream>>>(h1, Z, cc, roff, elist, U, N);

    // 8) final fused GEMM + pair-max epilogue
    k_mm2<<<slots2 * 8, 256, 0, stream>>>(U, W2t, (float*)d_out, N, nRow2, slots2);
}